// Round 3
// baseline (1007.594 us; speedup 1.0000x reference)
//
// v3 — identical algorithm to v2; resubmission after two UnresponsiveContainer infra failures.
#include <hip/hip_runtime.h>

#define N_NODES 50000
#define N_EDGES 800000
#define D_IN 96
#define D_HID 256
#define N_GRAPHS 64

// ---------------- CSR build ----------------
__global__ void k_count(const int* __restrict__ dst, int* __restrict__ deg, int E) {
    int e = blockIdx.x * blockDim.x + threadIdx.x;
    if (e < E) atomicAdd(&deg[dst[e]], 1);
}

__global__ __launch_bounds__(1024) void k_scan(const int* __restrict__ deg,
                                               int* __restrict__ rp,
                                               int* __restrict__ wp, int n) {
    __shared__ int sums[1024];
    int tid = threadIdx.x;
    int CH = (n + 1023) >> 10;  // 49 for n=50000
    int base = tid * CH;
    int s = 0;
    for (int i = 0; i < CH; i++) {
        int idx = base + i;
        if (idx < n) s += deg[idx];
    }
    sums[tid] = s;
    __syncthreads();
    for (int off = 1; off < 1024; off <<= 1) {
        int v = (tid >= off) ? sums[tid - off] : 0;
        __syncthreads();
        sums[tid] += v;
        __syncthreads();
    }
    int run = (tid == 0) ? 0 : sums[tid - 1];
    for (int i = 0; i < CH; i++) {
        int idx = base + i;
        if (idx < n) {
            rp[idx] = run;
            wp[idx] = run;
            run += deg[idx];
        }
    }
    if (tid == 1023) rp[n] = sums[1023];
}

__global__ void k_scatter(const int* __restrict__ src, const int* __restrict__ dst,
                          int* __restrict__ wp, int* __restrict__ csr, int E) {
    int e = blockIdx.x * blockDim.x + threadIdx.x;
    if (e < E) {
        int p = atomicAdd(&wp[dst[e]], 1);
        csr[p] = src[e];
    }
}

// ---------------- aggregation (wave per node) ----------------
// D=96: lanes 0..47 hold float2 each. h0 = x + sum_{src} x[src]
__global__ __launch_bounds__(256) void k_agg96(const float* __restrict__ x,
                                               const int* __restrict__ rp,
                                               const int* __restrict__ csr,
                                               float* __restrict__ h0, int n) {
    int wid = blockIdx.x * 4 + (threadIdx.x >> 6);
    if (wid >= n) return;
    int lane = threadIdx.x & 63;
    if (lane >= 48) return;
    int s = rp[wid], e = rp[wid + 1];
    const float2* xp = (const float2*)x;
    float2 acc = make_float2(0.f, 0.f);
    for (int j = s; j < e; j++) {
        int sc = csr[j];
        float2 v = xp[(size_t)sc * 48 + lane];
        acc.x += v.x; acc.y += v.y;
    }
    float2 xv = xp[(size_t)wid * 48 + lane];
    acc.x += xv.x; acc.y += xv.y;
    ((float2*)h0)[(size_t)wid * 48 + lane] = acc;
}

// D=256: all 64 lanes hold float4. out = h + sum_{src} h[src]
__global__ __launch_bounds__(256) void k_agg256(const float* __restrict__ h,
                                                const int* __restrict__ rp,
                                                const int* __restrict__ csr,
                                                float* __restrict__ outb, int n) {
    int wid = blockIdx.x * 4 + (threadIdx.x >> 6);
    if (wid >= n) return;
    int lane = threadIdx.x & 63;
    int s = rp[wid], e = rp[wid + 1];
    const float4* hp = (const float4*)h;
    float4 acc = make_float4(0.f, 0.f, 0.f, 0.f);
    for (int j = s; j < e; j++) {
        int sc = csr[j];
        float4 v = hp[(size_t)sc * 64 + lane];
        acc.x += v.x; acc.y += v.y; acc.z += v.z; acc.w += v.w;
    }
    float4 hv = hp[(size_t)wid * 64 + lane];
    acc.x += hv.x; acc.y += hv.y; acc.z += hv.z; acc.w += hv.w;
    ((float4*)outb)[(size_t)wid * 64 + lane] = acc;
}

// ---------------- f32 GEMM: C[M x 256] = act(A[M x K] @ W[K x 256] + bias) ----------------
// 128x128 tile, BK=32, 256 threads, 8x8 micro-tile.
template <int K, bool RELU>
__global__ __launch_bounds__(256) void gemm_fused(const float* __restrict__ A,
                                                  const float* __restrict__ W,
                                                  const float* __restrict__ bias,
                                                  float* __restrict__ C, int M) {
    constexpr int BM = 128, BN = 128, BK = 32;
    __shared__ float As[BK][BM + 4];  // k-major (transposed) A tile
    __shared__ float Bs[BK][BN + 4];
    const int tid = threadIdx.x;
    const int tx = tid & 15;
    const int ty = tid >> 4;
    const int row0 = blockIdx.x * BM;
    const int col0 = blockIdx.y * BN;

    float acc[8][8];
#pragma unroll
    for (int i = 0; i < 8; i++)
#pragma unroll
        for (int j = 0; j < 8; j++) acc[i][j] = 0.f;

    for (int kt = 0; kt < K; kt += BK) {
        // A tile: 128 rows x 32 k, float4 loads, transposed store
#pragma unroll
        for (int p = 0; p < 4; p++) {
            int idx4 = tid + p * 256;
            int m = idx4 >> 3;
            int k4 = idx4 & 7;
            int gr = row0 + m;
            float4 v = make_float4(0.f, 0.f, 0.f, 0.f);
            if (gr < M) v = *(const float4*)&A[(size_t)gr * K + kt + k4 * 4];
            As[k4 * 4 + 0][m] = v.x;
            As[k4 * 4 + 1][m] = v.y;
            As[k4 * 4 + 2][m] = v.z;
            As[k4 * 4 + 3][m] = v.w;
        }
        // B tile: 32 k x 128 n
#pragma unroll
        for (int p = 0; p < 4; p++) {
            int idx4 = tid + p * 256;
            int kk = idx4 >> 5;
            int n4 = idx4 & 31;
            *(float4*)&Bs[kk][n4 * 4] =
                *(const float4*)&W[(size_t)(kt + kk) * 256 + col0 + n4 * 4];
        }
        __syncthreads();
#pragma unroll
        for (int kk = 0; kk < BK; kk++) {
            float4 a0 = *(const float4*)&As[kk][ty * 8];
            float4 a1 = *(const float4*)&As[kk][ty * 8 + 4];
            float4 b0 = *(const float4*)&Bs[kk][tx * 8];
            float4 b1 = *(const float4*)&Bs[kk][tx * 8 + 4];
            float a[8] = {a0.x, a0.y, a0.z, a0.w, a1.x, a1.y, a1.z, a1.w};
            float b[8] = {b0.x, b0.y, b0.z, b0.w, b1.x, b1.y, b1.z, b1.w};
#pragma unroll
            for (int i = 0; i < 8; i++)
#pragma unroll
                for (int j = 0; j < 8; j++) acc[i][j] = fmaf(a[i], b[j], acc[i][j]);
        }
        __syncthreads();
    }

    float bb[8];
#pragma unroll
    for (int j = 0; j < 8; j++) bb[j] = bias[col0 + tx * 8 + j];
#pragma unroll
    for (int i = 0; i < 8; i++) {
        int gr = row0 + ty * 8 + i;
        if (gr < M) {
            float t[8];
#pragma unroll
            for (int j = 0; j < 8; j++) {
                float v = acc[i][j] + bb[j];
                if (RELU) v = fmaxf(v, 0.f);
                t[j] = v;
            }
            float* cp = &C[(size_t)gr * 256 + col0 + tx * 8];
            *(float4*)cp = make_float4(t[0], t[1], t[2], t[3]);
            *((float4*)cp + 1) = make_float4(t[4], t[5], t[6], t[7]);
        }
    }
}

// ---------------- pooling ----------------
__device__ __forceinline__ int lower_bound_i(const int* __restrict__ a, int n, int v) {
    int lo = 0, hi = n;
    while (lo < hi) {
        int mid = (lo + hi) >> 1;
        if (a[mid] < v) lo = mid + 1; else hi = mid;
    }
    return lo;
}

__global__ __launch_bounds__(64) void k_pool(const float* __restrict__ h,
                                             const int* __restrict__ batch,
                                             float* __restrict__ pooled, int n) {
    int g = blockIdx.x >> 2;
    int ch = blockIdx.x & 3;
    int lane = threadIdx.x;
    int s = lower_bound_i(batch, n, g);
    int e = lower_bound_i(batch, n, g + 1);
    float acc = 0.f;
    for (int r = s; r < e; r++) acc += h[(size_t)r * 256 + ch * 64 + lane];
    float cnt = (float)((e - s) > 1 ? (e - s) : 1);
    pooled[g * 256 + ch * 64 + lane] = acc / cnt;
}

__global__ __launch_bounds__(128) void k_head(const float* __restrict__ pooled,
                                              const float* __restrict__ Wl,
                                              const float* __restrict__ bl,
                                              float* __restrict__ out) {
    int tid = threadIdx.x;
    int g = tid >> 1, o = tid & 1;
    float s = bl[o];
    for (int k = 0; k < 256; k++) s = fmaf(pooled[g * 256 + k], Wl[k * 2 + o], s);
    out[g * 2 + o] = s;
}

// ---------------- launch ----------------
extern "C" void kernel_launch(void* const* d_in, const int* in_sizes, int n_in,
                              void* d_out, int out_size, void* d_ws, size_t ws_size,
                              hipStream_t stream) {
    const float* x = (const float*)d_in[0];
    const int* ei = (const int*)d_in[1];
    const int* batch = (const int*)d_in[2];
    const float* W1 = (const float*)d_in[3];
    const float* b1 = (const float*)d_in[4];
    const float* W2 = (const float*)d_in[5];
    const float* b2 = (const float*)d_in[6];
    const float* V1 = (const float*)d_in[7];
    const float* c1 = (const float*)d_in[8];
    const float* V2 = (const float*)d_in[9];
    const float* c2 = (const float*)d_in[10];
    const float* Wl = (const float*)d_in[11];
    const float* bl = (const float*)d_in[12];
    float* out = (float*)d_out;

    const int* srcp = ei;
    const int* dstp = ei + N_EDGES;

    char* ws = (char*)d_ws;
    size_t off = 0;
    auto alloc = [&](size_t bytes) {
        size_t o = off;
        off = (off + bytes + 255) & ~(size_t)255;
        return o;
    };
    size_t o_deg = alloc(sizeof(int) * (N_NODES + 1));
    size_t o_rp = alloc(sizeof(int) * (N_NODES + 1));
    size_t o_wp = alloc(sizeof(int) * (N_NODES + 1));
    size_t o_csr = alloc(sizeof(int) * N_EDGES);
    size_t o_h0 = alloc(sizeof(float) * (size_t)N_NODES * D_IN);
    size_t o_A = alloc(sizeof(float) * (size_t)N_NODES * D_HID);
    size_t o_B = alloc(sizeof(float) * (size_t)N_NODES * D_HID);
    size_t o_pool = alloc(sizeof(float) * N_GRAPHS * D_HID);
    (void)ws_size;

    int* deg = (int*)(ws + o_deg);
    int* rp = (int*)(ws + o_rp);
    int* wp = (int*)(ws + o_wp);
    int* csr = (int*)(ws + o_csr);
    float* h0 = (float*)(ws + o_h0);
    float* bufA = (float*)(ws + o_A);
    float* bufB = (float*)(ws + o_B);
    float* pooled = (float*)(ws + o_pool);

    hipMemsetAsync(deg, 0, sizeof(int) * (N_NODES + 1), stream);
    k_count<<<(N_EDGES + 255) / 256, 256, 0, stream>>>(dstp, deg, N_EDGES);
    k_scan<<<1, 1024, 0, stream>>>(deg, rp, wp, N_NODES);
    k_scatter<<<(N_EDGES + 255) / 256, 256, 0, stream>>>(srcp, dstp, wp, csr, N_EDGES);

    dim3 ggrid((N_NODES + 127) / 128, 2);

    // layer 1: h0 = x + agg(x); t1 = relu(h0@W1+b1) -> bufA; h1 = relu(t1@W2+b2) -> bufB
    k_agg96<<<(N_NODES + 3) / 4, 256, 0, stream>>>(x, rp, csr, h0, N_NODES);
    gemm_fused<96, true><<<ggrid, 256, 0, stream>>>(h0, W1, b1, bufA, N_NODES);
    gemm_fused<256, true><<<ggrid, 256, 0, stream>>>(bufA, W2, b2, bufB, N_NODES);

    // layer 2: g2 = h1 + agg(h1) -> bufA; t2 = relu(g2@V1+c1) -> bufB; h2 = t2@V2+c2 -> bufA
    k_agg256<<<(N_NODES + 3) / 4, 256, 0, stream>>>(bufB, rp, csr, bufA, N_NODES);
    gemm_fused<256, true><<<ggrid, 256, 0, stream>>>(bufA, V1, c1, bufB, N_NODES);
    gemm_fused<256, false><<<ggrid, 256, 0, stream>>>(bufB, V2, c2, bufA, N_NODES);

    // pool + head
    k_pool<<<N_GRAPHS * 4, 64, 0, stream>>>(bufA, batch, pooled, N_NODES);
    k_head<<<1, 128, 0, stream>>>(pooled, Wl, bl, out);
}

// Round 7
// 604.267 us; speedup vs baseline: 1.6675x; 1.6675x over previous
//
// v7 — bundle: (a) two-stage pooling fix (from v4, never yet measured),
// (b) MFMA bf16 GEMMs replacing f32 vector GEMMs. All inter-kernel buffers stay f32;
// GEMM converts A in staging, weights pre-transposed to bf16 Wt[n][k] once per call.
#include <hip/hip_runtime.h>

#define N_NODES 50000
#define N_EDGES 800000
#define D_IN 96
#define D_HID 256
#define N_GRAPHS 64

typedef __attribute__((ext_vector_type(8))) short bf16x8;
typedef __attribute__((ext_vector_type(4))) float f32x4;

__device__ __forceinline__ unsigned short f2bf(float f) {
    union { float f; unsigned int u; } v; v.f = f;
    unsigned int r = (v.u + 0x7FFFu + ((v.u >> 16) & 1u)) >> 16;  // RNE
    return (unsigned short)r;
}

// ---------------- CSR build ----------------
__global__ void k_count(const int* __restrict__ dst, int* __restrict__ deg, int E) {
    int e = blockIdx.x * blockDim.x + threadIdx.x;
    if (e < E) atomicAdd(&deg[dst[e]], 1);
}

__global__ __launch_bounds__(1024) void k_scan(const int* __restrict__ deg,
                                               int* __restrict__ rp,
                                               int* __restrict__ wp, int n) {
    __shared__ int sums[1024];
    int tid = threadIdx.x;
    int CH = (n + 1023) >> 10;
    int base = tid * CH;
    int s = 0;
    for (int i = 0; i < CH; i++) {
        int idx = base + i;
        if (idx < n) s += deg[idx];
    }
    sums[tid] = s;
    __syncthreads();
    for (int off = 1; off < 1024; off <<= 1) {
        int v = (tid >= off) ? sums[tid - off] : 0;
        __syncthreads();
        sums[tid] += v;
        __syncthreads();
    }
    int run = (tid == 0) ? 0 : sums[tid - 1];
    for (int i = 0; i < CH; i++) {
        int idx = base + i;
        if (idx < n) {
            rp[idx] = run;
            wp[idx] = run;
            run += deg[idx];
        }
    }
    if (tid == 1023) rp[n] = sums[1023];
}

__global__ void k_scatter(const int* __restrict__ src, const int* __restrict__ dst,
                          int* __restrict__ wp, int* __restrict__ csr, int E) {
    int e = blockIdx.x * blockDim.x + threadIdx.x;
    if (e < E) {
        int p = atomicAdd(&wp[dst[e]], 1);
        csr[p] = src[e];
    }
}

// ---------------- aggregation (wave per node, f32) ----------------
__global__ __launch_bounds__(256) void k_agg96(const float* __restrict__ x,
                                               const int* __restrict__ rp,
                                               const int* __restrict__ csr,
                                               float* __restrict__ h0, int n) {
    int wid = blockIdx.x * 4 + (threadIdx.x >> 6);
    if (wid >= n) return;
    int lane = threadIdx.x & 63;
    if (lane >= 48) return;
    int s = rp[wid], e = rp[wid + 1];
    const float2* xp = (const float2*)x;
    float2 acc = make_float2(0.f, 0.f);
    for (int j = s; j < e; j++) {
        int sc = csr[j];
        float2 v = xp[(size_t)sc * 48 + lane];
        acc.x += v.x; acc.y += v.y;
    }
    float2 xv = xp[(size_t)wid * 48 + lane];
    acc.x += xv.x; acc.y += xv.y;
    ((float2*)h0)[(size_t)wid * 48 + lane] = acc;
}

__global__ __launch_bounds__(256) void k_agg256(const float* __restrict__ h,
                                                const int* __restrict__ rp,
                                                const int* __restrict__ csr,
                                                float* __restrict__ outb, int n) {
    int wid = blockIdx.x * 4 + (threadIdx.x >> 6);
    if (wid >= n) return;
    int lane = threadIdx.x & 63;
    int s = rp[wid], e = rp[wid + 1];
    const float4* hp = (const float4*)h;
    float4 acc = make_float4(0.f, 0.f, 0.f, 0.f);
    for (int j = s; j < e; j++) {
        int sc = csr[j];
        float4 v = hp[(size_t)sc * 64 + lane];
        acc.x += v.x; acc.y += v.y; acc.z += v.z; acc.w += v.w;
    }
    float4 hv = hp[(size_t)wid * 64 + lane];
    acc.x += hv.x; acc.y += hv.y; acc.z += hv.z; acc.w += hv.w;
    ((float4*)outb)[(size_t)wid * 64 + lane] = acc;
}

// ---------------- weight transpose + bf16 convert: W[K][256] -> Wt[256][K] ----------------
__global__ __launch_bounds__(256) void k_wt(const float* __restrict__ W,
                                            unsigned short* __restrict__ Wt, int K) {
    int idx = blockIdx.x * 256 + threadIdx.x;
    if (idx >= K * 256) return;
    int k = idx >> 8;
    int n = idx & 255;
    Wt[(size_t)n * K + k] = f2bf(W[idx]);
}

// ---------------- MFMA bf16 GEMM: C[M x 256] = act(A[M x K] @ W + bias) ----------------
// A: f32 [M][K] (converted to bf16 in staging). Wt: bf16 [256][K] (pre-transposed).
// Block 64x128, BK=64, 4 waves (2x2), wave tile 32x64 (2x4 frags of 16x16x32).
// Fragment maps (HW-verified, learn_hip m89): A/B lane l: row/col=l&15, k=(l>>4)*8+e;
// C/D: col=lane&15, row=(lane>>4)*4+reg.
template <int K, bool RELU>
__global__ __launch_bounds__(256) void gemm_mfma(const float* __restrict__ A,
                                                 const unsigned short* __restrict__ Wt,
                                                 const float* __restrict__ bias,
                                                 float* __restrict__ C, int M) {
    constexpr int BM = 64, BN = 128, BK = 64;
    __shared__ unsigned short As[BM][BK + 8];  // +8 bf16 pad: 2-way conflicts only
    __shared__ unsigned short Bs[BN][BK + 8];
    const int tid = threadIdx.x;
    const int lane = tid & 63;
    const int wid = tid >> 6;
    const int wm = wid >> 1;  // 0..1
    const int wn = wid & 1;   // 0..1
    const int row0 = blockIdx.x * BM;
    const int col0 = blockIdx.y * BN;

    f32x4 acc[2][4];
#pragma unroll
    for (int f = 0; f < 2; f++)
#pragma unroll
        for (int g = 0; g < 4; g++) acc[f][g] = (f32x4){0.f, 0.f, 0.f, 0.f};

    for (int kt = 0; kt < K; kt += BK) {
        __syncthreads();
        // ---- stage A (f32 -> bf16): thread t: m=t>>2, kc=(t&3)*16
        {
            int m = tid >> 2;
            int kc = (tid & 3) * 16;
            int gr = row0 + m;
            float4 v[4];
#pragma unroll
            for (int i = 0; i < 4; i++) {
                int k = kt + kc + i * 4;
                if (gr < M && k < K)
                    v[i] = *(const float4*)&A[(size_t)gr * K + k];
                else
                    v[i] = make_float4(0.f, 0.f, 0.f, 0.f);
            }
            unsigned int pk[8];
#pragma unroll
            for (int i = 0; i < 4; i++) {
                pk[i * 2 + 0] = (unsigned int)f2bf(v[i].x) | ((unsigned int)f2bf(v[i].y) << 16);
                pk[i * 2 + 1] = (unsigned int)f2bf(v[i].z) | ((unsigned int)f2bf(v[i].w) << 16);
            }
            uint4* dst = (uint4*)&As[m][kc];
            dst[0] = make_uint4(pk[0], pk[1], pk[2], pk[3]);
            dst[1] = make_uint4(pk[4], pk[5], pk[6], pk[7]);
        }
        // ---- stage B (already bf16): thread t: n=t>>1, kc=(t&1)*32
        {
            int n = tid >> 1;
            int kc = (tid & 1) * 32;
            uint4 w[4];
#pragma unroll
            for (int i = 0; i < 4; i++) {
                int k = kt + kc + i * 8;
                if (k < K)
                    w[i] = *(const uint4*)&Wt[(size_t)(col0 + n) * K + k];
                else
                    w[i] = make_uint4(0u, 0u, 0u, 0u);
            }
            uint4* dst = (uint4*)&Bs[n][kc];
#pragma unroll
            for (int i = 0; i < 4; i++) dst[i] = w[i];
        }
        __syncthreads();
        // ---- compute: 2 k-steps of 32
#pragma unroll
        for (int ks = 0; ks < 2; ks++) {
            int ko = ks * 32 + (lane >> 4) * 8;
            bf16x8 af[2], bfr[4];
#pragma unroll
            for (int f = 0; f < 2; f++)
                af[f] = *(const bf16x8*)&As[wm * 32 + f * 16 + (lane & 15)][ko];
#pragma unroll
            for (int g = 0; g < 4; g++)
                bfr[g] = *(const bf16x8*)&Bs[wn * 64 + g * 16 + (lane & 15)][ko];
#pragma unroll
            for (int f = 0; f < 2; f++)
#pragma unroll
                for (int g = 0; g < 4; g++)
                    acc[f][g] = __builtin_amdgcn_mfma_f32_16x16x32_bf16(
                        af[f], bfr[g], acc[f][g], 0, 0, 0);
        }
    }

    // ---- epilogue: bias + act, scalar f32 stores (16-lane groups are 64B segments)
#pragma unroll
    for (int g = 0; g < 4; g++) {
        int n = col0 + wn * 64 + g * 16 + (lane & 15);
        float bb = bias[n];
#pragma unroll
        for (int f = 0; f < 2; f++) {
#pragma unroll
            for (int r = 0; r < 4; r++) {
                int m = row0 + wm * 32 + f * 16 + (lane >> 4) * 4 + r;
                if (m < M) {
                    float v = acc[f][g][r] + bb;
                    if (RELU) v = fmaxf(v, 0.f);
                    C[(size_t)m * 256 + n] = v;
                }
            }
        }
    }
}

// ---------------- pooling (two-stage, coalesced) ----------------
#define POOL_ROWS 64
__global__ __launch_bounds__(256) void k_pool_partial(const float* __restrict__ h,
                                                      const int* __restrict__ batch,
                                                      float* __restrict__ psum, int n) {
    int r0 = blockIdx.x * POOL_ROWS;
    int r1 = r0 + POOL_ROWS;
    if (r1 > n) r1 = n;
    if (r0 >= r1) return;
    int c = threadIdx.x;
    float acc = 0.f;
    int g = batch[r0];
    for (int r = r0; r < r1; r++) {
        int gr = batch[r];
        if (gr != g) {
            atomicAdd(&psum[g * 256 + c], acc);
            acc = 0.f;
            g = gr;
        }
        acc += h[(size_t)r * 256 + c];
    }
    atomicAdd(&psum[g * 256 + c], acc);
}

__device__ __forceinline__ int lower_bound_i(const int* __restrict__ a, int n, int v) {
    int lo = 0, hi = n;
    while (lo < hi) {
        int mid = (lo + hi) >> 1;
        if (a[mid] < v) lo = mid + 1; else hi = mid;
    }
    return lo;
}

__global__ __launch_bounds__(128) void k_head(const float* __restrict__ psum,
                                              const int* __restrict__ batch,
                                              const float* __restrict__ Wl,
                                              const float* __restrict__ bl,
                                              float* __restrict__ out, int n) {
    int tid = threadIdx.x;
    int g = tid >> 1, o = tid & 1;
    int s = lower_bound_i(batch, n, g);
    int e = lower_bound_i(batch, n, g + 1);
    float inv = 1.0f / (float)((e - s) > 1 ? (e - s) : 1);
    float sum = bl[o];
    for (int k = 0; k < 256; k++)
        sum = fmaf(psum[g * 256 + k] * inv, Wl[k * 2 + o], sum);
    out[g * 2 + o] = sum;
}

// ---------------- launch ----------------
extern "C" void kernel_launch(void* const* d_in, const int* in_sizes, int n_in,
                              void* d_out, int out_size, void* d_ws, size_t ws_size,
                              hipStream_t stream) {
    const float* x = (const float*)d_in[0];
    const int* ei = (const int*)d_in[1];
    const int* batch = (const int*)d_in[2];
    const float* W1 = (const float*)d_in[3];
    const float* b1 = (const float*)d_in[4];
    const float* W2 = (const float*)d_in[5];
    const float* b2 = (const float*)d_in[6];
    const float* V1 = (const float*)d_in[7];
    const float* c1 = (const float*)d_in[8];
    const float* V2 = (const float*)d_in[9];
    const float* c2 = (const float*)d_in[10];
    const float* Wl = (const float*)d_in[11];
    const float* bl = (const float*)d_in[12];
    float* out = (float*)d_out;

    const int* srcp = ei;
    const int* dstp = ei + N_EDGES;

    char* ws = (char*)d_ws;
    size_t off = 0;
    auto alloc = [&](size_t bytes) {
        size_t o = off;
        off = (off + bytes + 255) & ~(size_t)255;
        return o;
    };
    size_t o_deg = alloc(sizeof(int) * (N_NODES + 1));
    size_t o_rp = alloc(sizeof(int) * (N_NODES + 1));
    size_t o_wp = alloc(sizeof(int) * (N_NODES + 1));
    size_t o_csr = alloc(sizeof(int) * N_EDGES);
    size_t o_h0 = alloc(sizeof(float) * (size_t)N_NODES * D_IN);
    size_t o_A = alloc(sizeof(float) * (size_t)N_NODES * D_HID);
    size_t o_B = alloc(sizeof(float) * (size_t)N_NODES * D_HID);
    size_t o_pool = alloc(sizeof(float) * N_GRAPHS * D_HID);
    size_t o_wt1 = alloc(sizeof(unsigned short) * D_IN * D_HID);
    size_t o_wt2 = alloc(sizeof(unsigned short) * D_HID * D_HID);
    size_t o_wv1 = alloc(sizeof(unsigned short) * D_HID * D_HID);
    size_t o_wv2 = alloc(sizeof(unsigned short) * D_HID * D_HID);
    (void)ws_size;

    int* deg = (int*)(ws + o_deg);
    int* rp = (int*)(ws + o_rp);
    int* wp = (int*)(ws + o_wp);
    int* csr = (int*)(ws + o_csr);
    float* h0 = (float*)(ws + o_h0);
    float* bufA = (float*)(ws + o_A);
    float* bufB = (float*)(ws + o_B);
    float* psum = (float*)(ws + o_pool);
    unsigned short* wt1 = (unsigned short*)(ws + o_wt1);
    unsigned short* wt2 = (unsigned short*)(ws + o_wt2);
    unsigned short* wv1 = (unsigned short*)(ws + o_wv1);
    unsigned short* wv2 = (unsigned short*)(ws + o_wv2);

    hipMemsetAsync(deg, 0, sizeof(int) * (N_NODES + 1), stream);
    hipMemsetAsync(psum, 0, sizeof(float) * N_GRAPHS * D_HID, stream);

    // weight transposes (independent — enqueue first)
    k_wt<<<D_IN, 256, 0, stream>>>(W1, wt1, D_IN);
    k_wt<<<D_HID, 256, 0, stream>>>(W2, wt2, D_HID);
    k_wt<<<D_HID, 256, 0, stream>>>(V1, wv1, D_HID);
    k_wt<<<D_HID, 256, 0, stream>>>(V2, wv2, D_HID);

    k_count<<<(N_EDGES + 255) / 256, 256, 0, stream>>>(dstp, deg, N_EDGES);
    k_scan<<<1, 1024, 0, stream>>>(deg, rp, wp, N_NODES);
    k_scatter<<<(N_EDGES + 255) / 256, 256, 0, stream>>>(srcp, dstp, wp, csr, N_EDGES);

    dim3 ggrid((N_NODES + 63) / 64, 2);

    // layer 1: h0 = x + agg(x); t1 = relu(h0@W1+b1) -> bufA; h1 = relu(t1@W2+b2) -> bufB
    k_agg96<<<(N_NODES + 3) / 4, 256, 0, stream>>>(x, rp, csr, h0, N_NODES);
    gemm_mfma<96, true><<<ggrid, 256, 0, stream>>>(h0, wt1, b1, bufA, N_NODES);
    gemm_mfma<256, true><<<ggrid, 256, 0, stream>>>(bufA, wt2, b2, bufB, N_NODES);

    // layer 2: g2 = h1 + agg(h1) -> bufA; t2 = relu(g2@V1+c1) -> bufB; h2 = t2@V2+c2 -> bufA
    k_agg256<<<(N_NODES + 3) / 4, 256, 0, stream>>>(bufB, rp, csr, bufA, N_NODES);
    gemm_mfma<256, true><<<ggrid, 256, 0, stream>>>(bufA, wv1, c1, bufB, N_NODES);
    gemm_mfma<256, false><<<ggrid, 256, 0, stream>>>(bufB, wv2, c2, bufA, N_NODES);

    // pool + head
    k_pool_partial<<<(N_NODES + POOL_ROWS - 1) / POOL_ROWS, 256, 0, stream>>>(
        bufA, batch, psum, N_NODES);
    k_head<<<1, 128, 0, stream>>>(psum, batch, Wl, bl, out, N_NODES);
}

// Round 8
// 485.123 us; speedup vs baseline: 2.0770x; 1.2456x over previous
//
// v8 — replace single-block k_scan (127us, occ 0.15%) with 3-phase coalesced scan.
// Everything else identical to v7 (MFMA bf16 GEMMs + two-stage pooling).
#include <hip/hip_runtime.h>

#define N_NODES 50000
#define N_EDGES 800000
#define D_IN 96
#define D_HID 256
#define N_GRAPHS 64

#define SCAN_NB ((N_NODES + 255) / 256)  // 196 scan blocks

typedef __attribute__((ext_vector_type(8))) short bf16x8;
typedef __attribute__((ext_vector_type(4))) float f32x4;

__device__ __forceinline__ unsigned short f2bf(float f) {
    union { float f; unsigned int u; } v; v.f = f;
    unsigned int r = (v.u + 0x7FFFu + ((v.u >> 16) & 1u)) >> 16;  // RNE
    return (unsigned short)r;
}

// ---------------- CSR build ----------------
__global__ void k_count(const int* __restrict__ dst, int* __restrict__ deg, int E) {
    int e = blockIdx.x * blockDim.x + threadIdx.x;
    if (e < E) atomicAdd(&deg[dst[e]], 1);
}

// Phase 1: per-block sum of 256 degrees (coalesced)
__global__ __launch_bounds__(256) void k_scan1(const int* __restrict__ deg,
                                               int* __restrict__ bsum, int n) {
    __shared__ int red[256];
    int tid = threadIdx.x;
    int i = blockIdx.x * 256 + tid;
    red[tid] = (i < n) ? deg[i] : 0;
    __syncthreads();
    for (int off = 128; off > 0; off >>= 1) {
        if (tid < off) red[tid] += red[tid + off];
        __syncthreads();
    }
    if (tid == 0) bsum[blockIdx.x] = red[0];
}

// Phase 2: exclusive scan of block sums (nb <= 256), single block
__global__ __launch_bounds__(256) void k_scan2(int* __restrict__ bsum, int nb) {
    __shared__ int s[256];
    int tid = threadIdx.x;
    int v = (tid < nb) ? bsum[tid] : 0;
    s[tid] = v;
    __syncthreads();
    for (int off = 1; off < 256; off <<= 1) {
        int t = (tid >= off) ? s[tid - off] : 0;
        __syncthreads();
        s[tid] += t;
        __syncthreads();
    }
    if (tid < nb) bsum[tid] = s[tid] - v;  // exclusive
}

// Phase 3: local exclusive scan + block offset -> rp, wp. rp[n] = E (constant).
__global__ __launch_bounds__(256) void k_scan3(const int* __restrict__ deg,
                                               const int* __restrict__ bsum,
                                               int* __restrict__ rp,
                                               int* __restrict__ wp, int n) {
    __shared__ int s[256];
    int tid = threadIdx.x;
    int i = blockIdx.x * 256 + tid;
    int v = (i < n) ? deg[i] : 0;
    s[tid] = v;
    __syncthreads();
    for (int off = 1; off < 256; off <<= 1) {
        int t = (tid >= off) ? s[tid - off] : 0;
        __syncthreads();
        s[tid] += t;
        __syncthreads();
    }
    if (i < n) {
        int excl = s[tid] - v + bsum[blockIdx.x];
        rp[i] = excl;
        wp[i] = excl;
    }
    if (blockIdx.x == 0 && tid == 0) rp[n] = N_EDGES;
}

__global__ void k_scatter(const int* __restrict__ src, const int* __restrict__ dst,
                          int* __restrict__ wp, int* __restrict__ csr, int E) {
    int e = blockIdx.x * blockDim.x + threadIdx.x;
    if (e < E) {
        int p = atomicAdd(&wp[dst[e]], 1);
        csr[p] = src[e];
    }
}

// ---------------- aggregation (wave per node, f32) ----------------
__global__ __launch_bounds__(256) void k_agg96(const float* __restrict__ x,
                                               const int* __restrict__ rp,
                                               const int* __restrict__ csr,
                                               float* __restrict__ h0, int n) {
    int wid = blockIdx.x * 4 + (threadIdx.x >> 6);
    if (wid >= n) return;
    int lane = threadIdx.x & 63;
    if (lane >= 48) return;
    int s = rp[wid], e = rp[wid + 1];
    const float2* xp = (const float2*)x;
    float2 acc = make_float2(0.f, 0.f);
    for (int j = s; j < e; j++) {
        int sc = csr[j];
        float2 v = xp[(size_t)sc * 48 + lane];
        acc.x += v.x; acc.y += v.y;
    }
    float2 xv = xp[(size_t)wid * 48 + lane];
    acc.x += xv.x; acc.y += xv.y;
    ((float2*)h0)[(size_t)wid * 48 + lane] = acc;
}

__global__ __launch_bounds__(256) void k_agg256(const float* __restrict__ h,
                                                const int* __restrict__ rp,
                                                const int* __restrict__ csr,
                                                float* __restrict__ outb, int n) {
    int wid = blockIdx.x * 4 + (threadIdx.x >> 6);
    if (wid >= n) return;
    int lane = threadIdx.x & 63;
    int s = rp[wid], e = rp[wid + 1];
    const float4* hp = (const float4*)h;
    float4 acc = make_float4(0.f, 0.f, 0.f, 0.f);
    for (int j = s; j < e; j++) {
        int sc = csr[j];
        float4 v = hp[(size_t)sc * 64 + lane];
        acc.x += v.x; acc.y += v.y; acc.z += v.z; acc.w += v.w;
    }
    float4 hv = hp[(size_t)wid * 64 + lane];
    acc.x += hv.x; acc.y += hv.y; acc.z += hv.z; acc.w += hv.w;
    ((float4*)outb)[(size_t)wid * 64 + lane] = acc;
}

// ---------------- weight transpose + bf16 convert: W[K][256] -> Wt[256][K] ----------------
__global__ __launch_bounds__(256) void k_wt(const float* __restrict__ W,
                                            unsigned short* __restrict__ Wt, int K) {
    int idx = blockIdx.x * 256 + threadIdx.x;
    if (idx >= K * 256) return;
    int k = idx >> 8;
    int n = idx & 255;
    Wt[(size_t)n * K + k] = f2bf(W[idx]);
}

// ---------------- MFMA bf16 GEMM (unchanged from v7) ----------------
template <int K, bool RELU>
__global__ __launch_bounds__(256) void gemm_mfma(const float* __restrict__ A,
                                                 const unsigned short* __restrict__ Wt,
                                                 const float* __restrict__ bias,
                                                 float* __restrict__ C, int M) {
    constexpr int BM = 64, BN = 128, BK = 64;
    __shared__ unsigned short As[BM][BK + 8];
    __shared__ unsigned short Bs[BN][BK + 8];
    const int tid = threadIdx.x;
    const int lane = tid & 63;
    const int wid = tid >> 6;
    const int wm = wid >> 1;
    const int wn = wid & 1;
    const int row0 = blockIdx.x * BM;
    const int col0 = blockIdx.y * BN;

    f32x4 acc[2][4];
#pragma unroll
    for (int f = 0; f < 2; f++)
#pragma unroll
        for (int g = 0; g < 4; g++) acc[f][g] = (f32x4){0.f, 0.f, 0.f, 0.f};

    for (int kt = 0; kt < K; kt += BK) {
        __syncthreads();
        {
            int m = tid >> 2;
            int kc = (tid & 3) * 16;
            int gr = row0 + m;
            float4 v[4];
#pragma unroll
            for (int i = 0; i < 4; i++) {
                int k = kt + kc + i * 4;
                if (gr < M && k < K)
                    v[i] = *(const float4*)&A[(size_t)gr * K + k];
                else
                    v[i] = make_float4(0.f, 0.f, 0.f, 0.f);
            }
            unsigned int pk[8];
#pragma unroll
            for (int i = 0; i < 4; i++) {
                pk[i * 2 + 0] = (unsigned int)f2bf(v[i].x) | ((unsigned int)f2bf(v[i].y) << 16);
                pk[i * 2 + 1] = (unsigned int)f2bf(v[i].z) | ((unsigned int)f2bf(v[i].w) << 16);
            }
            uint4* dst = (uint4*)&As[m][kc];
            dst[0] = make_uint4(pk[0], pk[1], pk[2], pk[3]);
            dst[1] = make_uint4(pk[4], pk[5], pk[6], pk[7]);
        }
        {
            int n = tid >> 1;
            int kc = (tid & 1) * 32;
            uint4 w[4];
#pragma unroll
            for (int i = 0; i < 4; i++) {
                int k = kt + kc + i * 8;
                if (k < K)
                    w[i] = *(const uint4*)&Wt[(size_t)(col0 + n) * K + k];
                else
                    w[i] = make_uint4(0u, 0u, 0u, 0u);
            }
            uint4* dst = (uint4*)&Bs[n][kc];
#pragma unroll
            for (int i = 0; i < 4; i++) dst[i] = w[i];
        }
        __syncthreads();
#pragma unroll
        for (int ks = 0; ks < 2; ks++) {
            int ko = ks * 32 + (lane >> 4) * 8;
            bf16x8 af[2], bfr[4];
#pragma unroll
            for (int f = 0; f < 2; f++)
                af[f] = *(const bf16x8*)&As[wm * 32 + f * 16 + (lane & 15)][ko];
#pragma unroll
            for (int g = 0; g < 4; g++)
                bfr[g] = *(const bf16x8*)&Bs[wn * 64 + g * 16 + (lane & 15)][ko];
#pragma unroll
            for (int f = 0; f < 2; f++)
#pragma unroll
                for (int g = 0; g < 4; g++)
                    acc[f][g] = __builtin_amdgcn_mfma_f32_16x16x32_bf16(
                        af[f], bfr[g], acc[f][g], 0, 0, 0);
        }
    }

#pragma unroll
    for (int g = 0; g < 4; g++) {
        int n = col0 + wn * 64 + g * 16 + (lane & 15);
        float bb = bias[n];
#pragma unroll
        for (int f = 0; f < 2; f++) {
#pragma unroll
            for (int r = 0; r < 4; r++) {
                int m = row0 + wm * 32 + f * 16 + (lane >> 4) * 4 + r;
                if (m < M) {
                    float v = acc[f][g][r] + bb;
                    if (RELU) v = fmaxf(v, 0.f);
                    C[(size_t)m * 256 + n] = v;
                }
            }
        }
    }
}

// ---------------- pooling (two-stage, coalesced) ----------------
#define POOL_ROWS 64
__global__ __launch_bounds__(256) void k_pool_partial(const float* __restrict__ h,
                                                      const int* __restrict__ batch,
                                                      float* __restrict__ psum, int n) {
    int r0 = blockIdx.x * POOL_ROWS;
    int r1 = r0 + POOL_ROWS;
    if (r1 > n) r1 = n;
    if (r0 >= r1) return;
    int c = threadIdx.x;
    float acc = 0.f;
    int g = batch[r0];
    for (int r = r0; r < r1; r++) {
        int gr = batch[r];
        if (gr != g) {
            atomicAdd(&psum[g * 256 + c], acc);
            acc = 0.f;
            g = gr;
        }
        acc += h[(size_t)r * 256 + c];
    }
    atomicAdd(&psum[g * 256 + c], acc);
}

__device__ __forceinline__ int lower_bound_i(const int* __restrict__ a, int n, int v) {
    int lo = 0, hi = n;
    while (lo < hi) {
        int mid = (lo + hi) >> 1;
        if (a[mid] < v) lo = mid + 1; else hi = mid;
    }
    return lo;
}

__global__ __launch_bounds__(128) void k_head(const float* __restrict__ psum,
                                              const int* __restrict__ batch,
                                              const float* __restrict__ Wl,
                                              const float* __restrict__ bl,
                                              float* __restrict__ out, int n) {
    int tid = threadIdx.x;
    int g = tid >> 1, o = tid & 1;
    int s = lower_bound_i(batch, n, g);
    int e = lower_bound_i(batch, n, g + 1);
    float inv = 1.0f / (float)((e - s) > 1 ? (e - s) : 1);
    float sum = bl[o];
    for (int k = 0; k < 256; k++)
        sum = fmaf(psum[g * 256 + k] * inv, Wl[k * 2 + o], sum);
    out[g * 2 + o] = sum;
}

// ---------------- launch ----------------
extern "C" void kernel_launch(void* const* d_in, const int* in_sizes, int n_in,
                              void* d_out, int out_size, void* d_ws, size_t ws_size,
                              hipStream_t stream) {
    const float* x = (const float*)d_in[0];
    const int* ei = (const int*)d_in[1];
    const int* batch = (const int*)d_in[2];
    const float* W1 = (const float*)d_in[3];
    const float* b1 = (const float*)d_in[4];
    const float* W2 = (const float*)d_in[5];
    const float* b2 = (const float*)d_in[6];
    const float* V1 = (const float*)d_in[7];
    const float* c1 = (const float*)d_in[8];
    const float* V2 = (const float*)d_in[9];
    const float* c2 = (const float*)d_in[10];
    const float* Wl = (const float*)d_in[11];
    const float* bl = (const float*)d_in[12];
    float* out = (float*)d_out;

    const int* srcp = ei;
    const int* dstp = ei + N_EDGES;

    char* ws = (char*)d_ws;
    size_t off = 0;
    auto alloc = [&](size_t bytes) {
        size_t o = off;
        off = (off + bytes + 255) & ~(size_t)255;
        return o;
    };
    size_t o_deg = alloc(sizeof(int) * (N_NODES + 1));
    size_t o_rp = alloc(sizeof(int) * (N_NODES + 1));
    size_t o_wp = alloc(sizeof(int) * (N_NODES + 1));
    size_t o_bsum = alloc(sizeof(int) * SCAN_NB);
    size_t o_csr = alloc(sizeof(int) * N_EDGES);
    size_t o_h0 = alloc(sizeof(float) * (size_t)N_NODES * D_IN);
    size_t o_A = alloc(sizeof(float) * (size_t)N_NODES * D_HID);
    size_t o_B = alloc(sizeof(float) * (size_t)N_NODES * D_HID);
    size_t o_pool = alloc(sizeof(float) * N_GRAPHS * D_HID);
    size_t o_wt1 = alloc(sizeof(unsigned short) * D_IN * D_HID);
    size_t o_wt2 = alloc(sizeof(unsigned short) * D_HID * D_HID);
    size_t o_wv1 = alloc(sizeof(unsigned short) * D_HID * D_HID);
    size_t o_wv2 = alloc(sizeof(unsigned short) * D_HID * D_HID);
    (void)ws_size;

    int* deg = (int*)(ws + o_deg);
    int* rp = (int*)(ws + o_rp);
    int* wp = (int*)(ws + o_wp);
    int* bsum = (int*)(ws + o_bsum);
    int* csr = (int*)(ws + o_csr);
    float* h0 = (float*)(ws + o_h0);
    float* bufA = (float*)(ws + o_A);
    float* bufB = (float*)(ws + o_B);
    float* psum = (float*)(ws + o_pool);
    unsigned short* wt1 = (unsigned short*)(ws + o_wt1);
    unsigned short* wt2 = (unsigned short*)(ws + o_wt2);
    unsigned short* wv1 = (unsigned short*)(ws + o_wv1);
    unsigned short* wv2 = (unsigned short*)(ws + o_wv2);

    hipMemsetAsync(deg, 0, sizeof(int) * (N_NODES + 1), stream);
    hipMemsetAsync(psum, 0, sizeof(float) * N_GRAPHS * D_HID, stream);

    // weight transposes (independent — enqueue first)
    k_wt<<<D_IN, 256, 0, stream>>>(W1, wt1, D_IN);
    k_wt<<<D_HID, 256, 0, stream>>>(W2, wt2, D_HID);
    k_wt<<<D_HID, 256, 0, stream>>>(V1, wv1, D_HID);
    k_wt<<<D_HID, 256, 0, stream>>>(V2, wv2, D_HID);

    k_count<<<(N_EDGES + 255) / 256, 256, 0, stream>>>(dstp, deg, N_EDGES);
    k_scan1<<<SCAN_NB, 256, 0, stream>>>(deg, bsum, N_NODES);
    k_scan2<<<1, 256, 0, stream>>>(bsum, SCAN_NB);
    k_scan3<<<SCAN_NB, 256, 0, stream>>>(deg, bsum, rp, wp, N_NODES);
    k_scatter<<<(N_EDGES + 255) / 256, 256, 0, stream>>>(srcp, dstp, wp, csr, N_EDGES);

    dim3 ggrid((N_NODES + 63) / 64, 2);

    // layer 1
    k_agg96<<<(N_NODES + 3) / 4, 256, 0, stream>>>(x, rp, csr, h0, N_NODES);
    gemm_mfma<96, true><<<ggrid, 256, 0, stream>>>(h0, wt1, b1, bufA, N_NODES);
    gemm_mfma<256, true><<<ggrid, 256, 0, stream>>>(bufA, wt2, b2, bufB, N_NODES);

    // layer 2
    k_agg256<<<(N_NODES + 3) / 4, 256, 0, stream>>>(bufB, rp, csr, bufA, N_NODES);
    gemm_mfma<256, true><<<ggrid, 256, 0, stream>>>(bufA, wv1, c1, bufB, N_NODES);
    gemm_mfma<256, false><<<ggrid, 256, 0, stream>>>(bufB, wv2, c2, bufA, N_NODES);

    // pool + head
    k_pool_partial<<<(N_NODES + POOL_ROWS - 1) / POOL_ROWS, 256, 0, stream>>>(
        bufA, batch, psum, N_NODES);
    k_head<<<1, 128, 0, stream>>>(psum, batch, Wl, bl, out, N_NODES);
}

// Round 9
// 417.921 us; speedup vs baseline: 2.4110x; 1.1608x over previous
//
// v9 — all-bf16 activation pipeline: agg gathers and GEMM A/C in bf16 (f32 accumulate
// everywhere). Only h2 (pool input) stays f32. Rationale: k_agg256 is BW-bound
// (FETCH 397MB, 46% HBM); GEMM staging already rounded A to bf16, so storing bf16
// adds no new rounding except x/h1 pre-aggregation (~0.2% rel).
#include <hip/hip_runtime.h>

#define N_NODES 50000
#define N_EDGES 800000
#define D_IN 96
#define D_HID 256
#define N_GRAPHS 64

#define SCAN_NB ((N_NODES + 255) / 256)

typedef __attribute__((ext_vector_type(8))) short bf16x8;
typedef __attribute__((ext_vector_type(4))) float f32x4;

__device__ __forceinline__ unsigned short f2bf(float f) {
    union { float f; unsigned int u; } v; v.f = f;
    unsigned int r = (v.u + 0x7FFFu + ((v.u >> 16) & 1u)) >> 16;  // RNE
    return (unsigned short)r;
}
__device__ __forceinline__ float bfLo(unsigned int u) {
    union { unsigned int u; float f; } v; v.u = u << 16; return v.f;
}
__device__ __forceinline__ float bfHi(unsigned int u) {
    union { unsigned int u; float f; } v; v.u = u & 0xFFFF0000u; return v.f;
}
__device__ __forceinline__ unsigned int packbf(float a, float b) {
    return (unsigned int)f2bf(a) | ((unsigned int)f2bf(b) << 16);
}

// ---------------- CSR build ----------------
__global__ void k_count(const int* __restrict__ dst, int* __restrict__ deg, int E) {
    int e = blockIdx.x * blockDim.x + threadIdx.x;
    if (e < E) atomicAdd(&deg[dst[e]], 1);
}

__global__ __launch_bounds__(256) void k_scan1(const int* __restrict__ deg,
                                               int* __restrict__ bsum, int n) {
    __shared__ int red[256];
    int tid = threadIdx.x;
    int i = blockIdx.x * 256 + tid;
    red[tid] = (i < n) ? deg[i] : 0;
    __syncthreads();
    for (int off = 128; off > 0; off >>= 1) {
        if (tid < off) red[tid] += red[tid + off];
        __syncthreads();
    }
    if (tid == 0) bsum[blockIdx.x] = red[0];
}

__global__ __launch_bounds__(256) void k_scan2(int* __restrict__ bsum, int nb) {
    __shared__ int s[256];
    int tid = threadIdx.x;
    int v = (tid < nb) ? bsum[tid] : 0;
    s[tid] = v;
    __syncthreads();
    for (int off = 1; off < 256; off <<= 1) {
        int t = (tid >= off) ? s[tid - off] : 0;
        __syncthreads();
        s[tid] += t;
        __syncthreads();
    }
    if (tid < nb) bsum[tid] = s[tid] - v;
}

__global__ __launch_bounds__(256) void k_scan3(const int* __restrict__ deg,
                                               const int* __restrict__ bsum,
                                               int* __restrict__ rp,
                                               int* __restrict__ wp, int n) {
    __shared__ int s[256];
    int tid = threadIdx.x;
    int i = blockIdx.x * 256 + tid;
    int v = (i < n) ? deg[i] : 0;
    s[tid] = v;
    __syncthreads();
    for (int off = 1; off < 256; off <<= 1) {
        int t = (tid >= off) ? s[tid - off] : 0;
        __syncthreads();
        s[tid] += t;
        __syncthreads();
    }
    if (i < n) {
        int excl = s[tid] - v + bsum[blockIdx.x];
        rp[i] = excl;
        wp[i] = excl;
    }
    if (blockIdx.x == 0 && tid == 0) rp[n] = N_EDGES;
}

__global__ void k_scatter(const int* __restrict__ src, const int* __restrict__ dst,
                          int* __restrict__ wp, int* __restrict__ csr, int E) {
    int e = blockIdx.x * blockDim.x + threadIdx.x;
    if (e < E) {
        int p = atomicAdd(&wp[dst[e]], 1);
        csr[p] = src[e];
    }
}

// ---------------- x f32 -> bf16 ----------------
__global__ __launch_bounds__(256) void k_x2bf(const float* __restrict__ x,
                                              unsigned short* __restrict__ xb, int n4) {
    int i = blockIdx.x * 256 + threadIdx.x;
    if (i >= n4) return;
    float4 v = ((const float4*)x)[i];
    ((uint2*)xb)[i] = make_uint2(packbf(v.x, v.y), packbf(v.z, v.w));
}

// ---------------- aggregation (wave per node, bf16 in/out, f32 accum) ----------------
// D=96: lanes 0..47 hold 2 bf16 (1 uint) each.
__global__ __launch_bounds__(256) void k_agg96b(const unsigned short* __restrict__ xb,
                                                const int* __restrict__ rp,
                                                const int* __restrict__ csr,
                                                unsigned short* __restrict__ h0, int n) {
    int wid = blockIdx.x * 4 + (threadIdx.x >> 6);
    if (wid >= n) return;
    int lane = threadIdx.x & 63;
    if (lane >= 48) return;
    int s = rp[wid], e = rp[wid + 1];
    const unsigned int* xp = (const unsigned int*)xb;
    float ax = 0.f, ay = 0.f;
    for (int j = s; j < e; j++) {
        int sc = csr[j];
        unsigned int u = xp[(size_t)sc * 48 + lane];
        ax += bfLo(u); ay += bfHi(u);
    }
    unsigned int u = xp[(size_t)wid * 48 + lane];
    ax += bfLo(u); ay += bfHi(u);
    ((unsigned int*)h0)[(size_t)wid * 48 + lane] = packbf(ax, ay);
}

// D=256: all 64 lanes hold 4 bf16 (uint2) each.
__global__ __launch_bounds__(256) void k_agg256b(const unsigned short* __restrict__ h,
                                                 const int* __restrict__ rp,
                                                 const int* __restrict__ csr,
                                                 unsigned short* __restrict__ outb, int n) {
    int wid = blockIdx.x * 4 + (threadIdx.x >> 6);
    if (wid >= n) return;
    int lane = threadIdx.x & 63;
    int s = rp[wid], e = rp[wid + 1];
    const uint2* hp = (const uint2*)h;
    float a0 = 0.f, a1 = 0.f, a2 = 0.f, a3 = 0.f;
    for (int j = s; j < e; j++) {
        int sc = csr[j];
        uint2 v = hp[(size_t)sc * 64 + lane];
        a0 += bfLo(v.x); a1 += bfHi(v.x);
        a2 += bfLo(v.y); a3 += bfHi(v.y);
    }
    uint2 v = hp[(size_t)wid * 64 + lane];
    a0 += bfLo(v.x); a1 += bfHi(v.x);
    a2 += bfLo(v.y); a3 += bfHi(v.y);
    ((uint2*)outb)[(size_t)wid * 64 + lane] = make_uint2(packbf(a0, a1), packbf(a2, a3));
}

// ---------------- weight transpose + bf16: W[K][256] -> Wt[256][K] ----------------
__global__ __launch_bounds__(256) void k_wt(const float* __restrict__ W,
                                            unsigned short* __restrict__ Wt, int K) {
    int idx = blockIdx.x * 256 + threadIdx.x;
    if (idx >= K * 256) return;
    int k = idx >> 8;
    int n = idx & 255;
    Wt[(size_t)n * K + k] = f2bf(W[idx]);
}

// ---------------- MFMA bf16 GEMM: C[M x 256] = act(A[M x K] @ W + bias) ----------------
// A: bf16 [M][K]. Wt: bf16 [256][K]. C: bf16 or f32 per OUTBF.
template <int K, bool RELU, bool OUTBF>
__global__ __launch_bounds__(256) void gemm_mfma(const unsigned short* __restrict__ A,
                                                 const unsigned short* __restrict__ Wt,
                                                 const float* __restrict__ bias,
                                                 void* __restrict__ Cv, int M) {
    constexpr int BM = 64, BN = 128, BK = 64;
    __shared__ unsigned short As[BM][BK + 8];
    __shared__ unsigned short Bs[BN][BK + 8];
    const int tid = threadIdx.x;
    const int lane = tid & 63;
    const int wid = tid >> 6;
    const int wm = wid >> 1;
    const int wn = wid & 1;
    const int row0 = blockIdx.x * BM;
    const int col0 = blockIdx.y * BN;

    f32x4 acc[2][4];
#pragma unroll
    for (int f = 0; f < 2; f++)
#pragma unroll
        for (int g = 0; g < 4; g++) acc[f][g] = (f32x4){0.f, 0.f, 0.f, 0.f};

    for (int kt = 0; kt < K; kt += BK) {
        __syncthreads();
        // stage A (bf16 direct): thread t: m=t>>2, kc=(t&3)*16 -> 2x uint4
        {
            int m = tid >> 2;
            int kc = (tid & 3) * 16;
            int gr = row0 + m;
            uint4 w0 = make_uint4(0u, 0u, 0u, 0u), w1 = w0;
            int k = kt + kc;
            if (gr < M && k < K) {
                w0 = *(const uint4*)&A[(size_t)gr * K + k];
                if (k + 8 < K) w1 = *(const uint4*)&A[(size_t)gr * K + k + 8];
            }
            uint4* dst = (uint4*)&As[m][kc];
            dst[0] = w0; dst[1] = w1;
        }
        // stage B: thread t: n=t>>1, kc=(t&1)*32 -> 4x uint4
        {
            int n = tid >> 1;
            int kc = (tid & 1) * 32;
            uint4 w[4];
#pragma unroll
            for (int i = 0; i < 4; i++) {
                int k = kt + kc + i * 8;
                if (k < K)
                    w[i] = *(const uint4*)&Wt[(size_t)(col0 + n) * K + k];
                else
                    w[i] = make_uint4(0u, 0u, 0u, 0u);
            }
            uint4* dst = (uint4*)&Bs[n][kc];
#pragma unroll
            for (int i = 0; i < 4; i++) dst[i] = w[i];
        }
        __syncthreads();
#pragma unroll
        for (int ks = 0; ks < 2; ks++) {
            int ko = ks * 32 + (lane >> 4) * 8;
            bf16x8 af[2], bfr[4];
#pragma unroll
            for (int f = 0; f < 2; f++)
                af[f] = *(const bf16x8*)&As[wm * 32 + f * 16 + (lane & 15)][ko];
#pragma unroll
            for (int g = 0; g < 4; g++)
                bfr[g] = *(const bf16x8*)&Bs[wn * 64 + g * 16 + (lane & 15)][ko];
#pragma unroll
            for (int f = 0; f < 2; f++)
#pragma unroll
                for (int g = 0; g < 4; g++)
                    acc[f][g] = __builtin_amdgcn_mfma_f32_16x16x32_bf16(
                        af[f], bfr[g], acc[f][g], 0, 0, 0);
        }
    }

#pragma unroll
    for (int g = 0; g < 4; g++) {
        int n = col0 + wn * 64 + g * 16 + (lane & 15);
        float bb = bias[n];
#pragma unroll
        for (int f = 0; f < 2; f++) {
#pragma unroll
            for (int r = 0; r < 4; r++) {
                int m = row0 + wm * 32 + f * 16 + (lane >> 4) * 4 + r;
                if (m < M) {
                    float v = acc[f][g][r] + bb;
                    if (RELU) v = fmaxf(v, 0.f);
                    if (OUTBF)
                        ((unsigned short*)Cv)[(size_t)m * 256 + n] = f2bf(v);
                    else
                        ((float*)Cv)[(size_t)m * 256 + n] = v;
                }
            }
        }
    }
}

// ---------------- pooling (two-stage, f32 input) ----------------
#define POOL_ROWS 64
__global__ __launch_bounds__(256) void k_pool_partial(const float* __restrict__ h,
                                                      const int* __restrict__ batch,
                                                      float* __restrict__ psum, int n) {
    int r0 = blockIdx.x * POOL_ROWS;
    int r1 = r0 + POOL_ROWS;
    if (r1 > n) r1 = n;
    if (r0 >= r1) return;
    int c = threadIdx.x;
    float acc = 0.f;
    int g = batch[r0];
    for (int r = r0; r < r1; r++) {
        int gr = batch[r];
        if (gr != g) {
            atomicAdd(&psum[g * 256 + c], acc);
            acc = 0.f;
            g = gr;
        }
        acc += h[(size_t)r * 256 + c];
    }
    atomicAdd(&psum[g * 256 + c], acc);
}

__device__ __forceinline__ int lower_bound_i(const int* __restrict__ a, int n, int v) {
    int lo = 0, hi = n;
    while (lo < hi) {
        int mid = (lo + hi) >> 1;
        if (a[mid] < v) lo = mid + 1; else hi = mid;
    }
    return lo;
}

__global__ __launch_bounds__(128) void k_head(const float* __restrict__ psum,
                                              const int* __restrict__ batch,
                                              const float* __restrict__ Wl,
                                              const float* __restrict__ bl,
                                              float* __restrict__ out, int n) {
    int tid = threadIdx.x;
    int g = tid >> 1, o = tid & 1;
    int s = lower_bound_i(batch, n, g);
    int e = lower_bound_i(batch, n, g + 1);
    float inv = 1.0f / (float)((e - s) > 1 ? (e - s) : 1);
    float sum = bl[o];
    for (int k = 0; k < 256; k++)
        sum = fmaf(psum[g * 256 + k] * inv, Wl[k * 2 + o], sum);
    out[g * 2 + o] = sum;
}

// ---------------- launch ----------------
extern "C" void kernel_launch(void* const* d_in, const int* in_sizes, int n_in,
                              void* d_out, int out_size, void* d_ws, size_t ws_size,
                              hipStream_t stream) {
    const float* x = (const float*)d_in[0];
    const int* ei = (const int*)d_in[1];
    const int* batch = (const int*)d_in[2];
    const float* W1 = (const float*)d_in[3];
    const float* b1 = (const float*)d_in[4];
    const float* W2 = (const float*)d_in[5];
    const float* b2 = (const float*)d_in[6];
    const float* V1 = (const float*)d_in[7];
    const float* c1 = (const float*)d_in[8];
    const float* V2 = (const float*)d_in[9];
    const float* c2 = (const float*)d_in[10];
    const float* Wl = (const float*)d_in[11];
    const float* bl = (const float*)d_in[12];
    float* out = (float*)d_out;

    const int* srcp = ei;
    const int* dstp = ei + N_EDGES;

    char* ws = (char*)d_ws;
    size_t off = 0;
    auto alloc = [&](size_t bytes) {
        size_t o = off;
        off = (off + bytes + 255) & ~(size_t)255;
        return o;
    };
    size_t o_deg = alloc(sizeof(int) * (N_NODES + 1));
    size_t o_rp = alloc(sizeof(int) * (N_NODES + 1));
    size_t o_wp = alloc(sizeof(int) * (N_NODES + 1));
    size_t o_bsum = alloc(sizeof(int) * SCAN_NB);
    size_t o_csr = alloc(sizeof(int) * N_EDGES);
    size_t o_B1 = alloc(sizeof(unsigned short) * (size_t)N_NODES * D_HID);  // rotating bf16
    size_t o_B2 = alloc(sizeof(unsigned short) * (size_t)N_NODES * D_HID);  // rotating bf16
    size_t o_h2 = alloc(sizeof(float) * (size_t)N_NODES * D_HID);           // f32 pool input
    size_t o_pool = alloc(sizeof(float) * N_GRAPHS * D_HID);
    size_t o_wt1 = alloc(sizeof(unsigned short) * D_IN * D_HID);
    size_t o_wt2 = alloc(sizeof(unsigned short) * D_HID * D_HID);
    size_t o_wv1 = alloc(sizeof(unsigned short) * D_HID * D_HID);
    size_t o_wv2 = alloc(sizeof(unsigned short) * D_HID * D_HID);
    (void)ws_size;

    int* deg = (int*)(ws + o_deg);
    int* rp = (int*)(ws + o_rp);
    int* wp = (int*)(ws + o_wp);
    int* bsum = (int*)(ws + o_bsum);
    int* csr = (int*)(ws + o_csr);
    unsigned short* B1 = (unsigned short*)(ws + o_B1);
    unsigned short* B2 = (unsigned short*)(ws + o_B2);
    float* h2 = (float*)(ws + o_h2);
    float* psum = (float*)(ws + o_pool);
    unsigned short* wt1 = (unsigned short*)(ws + o_wt1);
    unsigned short* wt2 = (unsigned short*)(ws + o_wt2);
    unsigned short* wv1 = (unsigned short*)(ws + o_wv1);
    unsigned short* wv2 = (unsigned short*)(ws + o_wv2);

    hipMemsetAsync(deg, 0, sizeof(int) * (N_NODES + 1), stream);
    hipMemsetAsync(psum, 0, sizeof(float) * N_GRAPHS * D_HID, stream);

    k_wt<<<D_IN, 256, 0, stream>>>(W1, wt1, D_IN);
    k_wt<<<D_HID, 256, 0, stream>>>(W2, wt2, D_HID);
    k_wt<<<D_HID, 256, 0, stream>>>(V1, wv1, D_HID);
    k_wt<<<D_HID, 256, 0, stream>>>(V2, wv2, D_HID);

    k_count<<<(N_EDGES + 255) / 256, 256, 0, stream>>>(dstp, deg, N_EDGES);
    k_scan1<<<SCAN_NB, 256, 0, stream>>>(deg, bsum, N_NODES);
    k_scan2<<<1, 256, 0, stream>>>(bsum, SCAN_NB);
    k_scan3<<<SCAN_NB, 256, 0, stream>>>(deg, bsum, rp, wp, N_NODES);
    k_scatter<<<(N_EDGES + 255) / 256, 256, 0, stream>>>(srcp, dstp, wp, csr, N_EDGES);

    // x -> bf16 (into B1)
    k_x2bf<<<(N_NODES * D_IN / 4 + 255) / 256, 256, 0, stream>>>(x, B1, N_NODES * D_IN / 4);

    dim3 ggrid((N_NODES + 63) / 64, 2);

    // layer 1: h0 = xb + agg(xb) -> B2; t1 = relu(h0@W1+b1) -> B1; h1 = relu(t1@W2+b2) -> B2
    k_agg96b<<<(N_NODES + 3) / 4, 256, 0, stream>>>(B1, rp, csr, B2, N_NODES);
    gemm_mfma<96, true, true><<<ggrid, 256, 0, stream>>>(B2, wt1, b1, B1, N_NODES);
    gemm_mfma<256, true, true><<<ggrid, 256, 0, stream>>>(B1, wt2, b2, B2, N_NODES);

    // layer 2: g2 = h1 + agg(h1) -> B1; t2 = relu(g2@V1+c1) -> B2; h2 = t2@V2+c2 -> h2(f32)
    k_agg256b<<<(N_NODES + 3) / 4, 256, 0, stream>>>(B2, rp, csr, B1, N_NODES);
    gemm_mfma<256, true, true><<<ggrid, 256, 0, stream>>>(B1, wv1, c1, B2, N_NODES);
    gemm_mfma<256, false, false><<<ggrid, 256, 0, stream>>>(B2, wv2, c2, h2, N_NODES);

    // pool + head
    k_pool_partial<<<(N_NODES + POOL_ROWS - 1) / POOL_ROWS, 256, 0, stream>>>(
        h2, batch, psum, N_NODES);
    k_head<<<1, 128, 0, stream>>>(psum, batch, Wl, bl, out, N_NODES);
}

// Round 11
// 350.675 us; speedup vs baseline: 2.8733x; 1.1918x over previous
//
// v11 — identical to v10 (multi-edge aggregation); resubmission after UnresponsiveContainer.
#include <hip/hip_runtime.h>

#define N_NODES 50000
#define N_EDGES 800000
#define D_IN 96
#define D_HID 256
#define N_GRAPHS 64

#define SCAN_NB ((N_NODES + 255) / 256)

typedef __attribute__((ext_vector_type(8))) short bf16x8;
typedef __attribute__((ext_vector_type(4))) float f32x4;

__device__ __forceinline__ unsigned short f2bf(float f) {
    union { float f; unsigned int u; } v; v.f = f;
    unsigned int r = (v.u + 0x7FFFu + ((v.u >> 16) & 1u)) >> 16;  // RNE
    return (unsigned short)r;
}
__device__ __forceinline__ float bfLo(unsigned int u) {
    union { unsigned int u; float f; } v; v.u = u << 16; return v.f;
}
__device__ __forceinline__ float bfHi(unsigned int u) {
    union { unsigned int u; float f; } v; v.u = u & 0xFFFF0000u; return v.f;
}
__device__ __forceinline__ unsigned int packbf(float a, float b) {
    return (unsigned int)f2bf(a) | ((unsigned int)f2bf(b) << 16);
}

// ---------------- CSR build ----------------
__global__ void k_count(const int* __restrict__ dst, int* __restrict__ deg, int E) {
    int e = blockIdx.x * blockDim.x + threadIdx.x;
    if (e < E) atomicAdd(&deg[dst[e]], 1);
}

__global__ __launch_bounds__(256) void k_scan1(const int* __restrict__ deg,
                                               int* __restrict__ bsum, int n) {
    __shared__ int red[256];
    int tid = threadIdx.x;
    int i = blockIdx.x * 256 + tid;
    red[tid] = (i < n) ? deg[i] : 0;
    __syncthreads();
    for (int off = 128; off > 0; off >>= 1) {
        if (tid < off) red[tid] += red[tid + off];
        __syncthreads();
    }
    if (tid == 0) bsum[blockIdx.x] = red[0];
}

__global__ __launch_bounds__(256) void k_scan2(int* __restrict__ bsum, int nb) {
    __shared__ int s[256];
    int tid = threadIdx.x;
    int v = (tid < nb) ? bsum[tid] : 0;
    s[tid] = v;
    __syncthreads();
    for (int off = 1; off < 256; off <<= 1) {
        int t = (tid >= off) ? s[tid - off] : 0;
        __syncthreads();
        s[tid] += t;
        __syncthreads();
    }
    if (tid < nb) bsum[tid] = s[tid] - v;
}

__global__ __launch_bounds__(256) void k_scan3(const int* __restrict__ deg,
                                               const int* __restrict__ bsum,
                                               int* __restrict__ rp,
                                               int* __restrict__ wp, int n) {
    __shared__ int s[256];
    int tid = threadIdx.x;
    int i = blockIdx.x * 256 + tid;
    int v = (i < n) ? deg[i] : 0;
    s[tid] = v;
    __syncthreads();
    for (int off = 1; off < 256; off <<= 1) {
        int t = (tid >= off) ? s[tid - off] : 0;
        __syncthreads();
        s[tid] += t;
        __syncthreads();
    }
    if (i < n) {
        int excl = s[tid] - v + bsum[blockIdx.x];
        rp[i] = excl;
        wp[i] = excl;
    }
    if (blockIdx.x == 0 && tid == 0) rp[n] = N_EDGES;
}

__global__ void k_scatter(const int* __restrict__ src, const int* __restrict__ dst,
                          int* __restrict__ wp, int* __restrict__ csr, int E) {
    int e = blockIdx.x * blockDim.x + threadIdx.x;
    if (e < E) {
        int p = atomicAdd(&wp[dst[e]], 1);
        csr[p] = src[e];
    }
}

// ---------------- x f32 -> bf16 ----------------
__global__ __launch_bounds__(256) void k_x2bf(const float* __restrict__ x,
                                              unsigned short* __restrict__ xb, int n4) {
    int i = blockIdx.x * 256 + threadIdx.x;
    if (i >= n4) return;
    float4 v = ((const float4*)x)[i];
    ((uint2*)xb)[i] = make_uint2(packbf(v.x, v.y), packbf(v.z, v.w));
}

// ---------------- aggregation ----------------
// D=96 bf16: row = 192B = 12 uint4. 4 groups x 12 lanes, 4 edges per iteration.
__global__ __launch_bounds__(256) void k_agg96b(const unsigned short* __restrict__ xb,
                                                const int* __restrict__ rp,
                                                const int* __restrict__ csr,
                                                unsigned short* __restrict__ h0, int n) {
    int wid = blockIdx.x * 4 + (threadIdx.x >> 6);
    if (wid >= n) return;
    int lane = threadIdx.x & 63;
    int grp = lane / 12;       // 0..3 active, 4..5 idle
    int sub = lane % 12;
    int s = rp[wid], e = rp[wid + 1];
    const uint4* xp = (const uint4*)xb;  // row stride = 12 uint4
    float a[8] = {0.f, 0.f, 0.f, 0.f, 0.f, 0.f, 0.f, 0.f};
    if (lane < 48) {
        for (int j = s + grp; j < e; j += 4) {
            int sc = csr[j];
            uint4 v = xp[(size_t)sc * 12 + sub];
            a[0] += bfLo(v.x); a[1] += bfHi(v.x);
            a[2] += bfLo(v.y); a[3] += bfHi(v.y);
            a[4] += bfLo(v.z); a[5] += bfHi(v.z);
            a[6] += bfLo(v.w); a[7] += bfHi(v.w);
        }
    }
    // group-tree reduce: (g0+=g2, g1+=g3), then g0+=g1. Lanes >=48 hold zeros.
#pragma unroll
    for (int i = 0; i < 8; i++) a[i] += __shfl(a[i], lane + 24, 64);
#pragma unroll
    for (int i = 0; i < 8; i++) a[i] += __shfl(a[i], lane + 12, 64);
    if (lane < 12) {
        uint4 v = xp[(size_t)wid * 12 + sub];  // self row
        a[0] += bfLo(v.x); a[1] += bfHi(v.x);
        a[2] += bfLo(v.y); a[3] += bfHi(v.y);
        a[4] += bfLo(v.z); a[5] += bfHi(v.z);
        a[6] += bfLo(v.w); a[7] += bfHi(v.w);
        uint4 o;
        o.x = packbf(a[0], a[1]); o.y = packbf(a[2], a[3]);
        o.z = packbf(a[4], a[5]); o.w = packbf(a[6], a[7]);
        ((uint4*)h0)[(size_t)wid * 12 + sub] = o;
    }
}

// D=256 bf16: row = 512B = 32 uint4. 2 half-waves, 2 edges per iteration.
__global__ __launch_bounds__(256) void k_agg256b(const unsigned short* __restrict__ h,
                                                 const int* __restrict__ rp,
                                                 const int* __restrict__ csr,
                                                 unsigned short* __restrict__ outb, int n) {
    int wid = blockIdx.x * 4 + (threadIdx.x >> 6);
    if (wid >= n) return;
    int lane = threadIdx.x & 63;
    int half = lane >> 5;
    int sub = lane & 31;
    int s = rp[wid], e = rp[wid + 1];
    const uint4* hp = (const uint4*)h;  // row stride = 32 uint4
    float a[8] = {0.f, 0.f, 0.f, 0.f, 0.f, 0.f, 0.f, 0.f};
    for (int j = s + half; j < e; j += 2) {
        int sc = csr[j];
        uint4 v = hp[(size_t)sc * 32 + sub];
        a[0] += bfLo(v.x); a[1] += bfHi(v.x);
        a[2] += bfLo(v.y); a[3] += bfHi(v.y);
        a[4] += bfLo(v.z); a[5] += bfHi(v.z);
        a[6] += bfLo(v.w); a[7] += bfHi(v.w);
    }
    // cross-half reduce: half0 lane gets half1 partial
#pragma unroll
    for (int i = 0; i < 8; i++) a[i] += __shfl(a[i], sub + 32, 64);
    if (half == 0) {
        uint4 v = hp[(size_t)wid * 32 + sub];  // self row
        a[0] += bfLo(v.x); a[1] += bfHi(v.x);
        a[2] += bfLo(v.y); a[3] += bfHi(v.y);
        a[4] += bfLo(v.z); a[5] += bfHi(v.z);
        a[6] += bfLo(v.w); a[7] += bfHi(v.w);
        uint4 o;
        o.x = packbf(a[0], a[1]); o.y = packbf(a[2], a[3]);
        o.z = packbf(a[4], a[5]); o.w = packbf(a[6], a[7]);
        ((uint4*)outb)[(size_t)wid * 32 + sub] = o;
    }
}

// ---------------- weight transpose + bf16: W[K][256] -> Wt[256][K] ----------------
__global__ __launch_bounds__(256) void k_wt(const float* __restrict__ W,
                                            unsigned short* __restrict__ Wt, int K) {
    int idx = blockIdx.x * 256 + threadIdx.x;
    if (idx >= K * 256) return;
    int k = idx >> 8;
    int n = idx & 255;
    Wt[(size_t)n * K + k] = f2bf(W[idx]);
}

// ---------------- MFMA bf16 GEMM (unchanged from v9) ----------------
template <int K, bool RELU, bool OUTBF>
__global__ __launch_bounds__(256) void gemm_mfma(const unsigned short* __restrict__ A,
                                                 const unsigned short* __restrict__ Wt,
                                                 const float* __restrict__ bias,
                                                 void* __restrict__ Cv, int M) {
    constexpr int BM = 64, BN = 128, BK = 64;
    __shared__ unsigned short As[BM][BK + 8];
    __shared__ unsigned short Bs[BN][BK + 8];
    const int tid = threadIdx.x;
    const int lane = tid & 63;
    const int wid = tid >> 6;
    const int wm = wid >> 1;
    const int wn = wid & 1;
    const int row0 = blockIdx.x * BM;
    const int col0 = blockIdx.y * BN;

    f32x4 acc[2][4];
#pragma unroll
    for (int f = 0; f < 2; f++)
#pragma unroll
        for (int g = 0; g < 4; g++) acc[f][g] = (f32x4){0.f, 0.f, 0.f, 0.f};

    for (int kt = 0; kt < K; kt += BK) {
        __syncthreads();
        {
            int m = tid >> 2;
            int kc = (tid & 3) * 16;
            int gr = row0 + m;
            uint4 w0 = make_uint4(0u, 0u, 0u, 0u), w1 = w0;
            int k = kt + kc;
            if (gr < M && k < K) {
                w0 = *(const uint4*)&A[(size_t)gr * K + k];
                if (k + 8 < K) w1 = *(const uint4*)&A[(size_t)gr * K + k + 8];
            }
            uint4* dst = (uint4*)&As[m][kc];
            dst[0] = w0; dst[1] = w1;
        }
        {
            int n = tid >> 1;
            int kc = (tid & 1) * 32;
            uint4 w[4];
#pragma unroll
            for (int i = 0; i < 4; i++) {
                int k = kt + kc + i * 8;
                if (k < K)
                    w[i] = *(const uint4*)&Wt[(size_t)(col0 + n) * K + k];
                else
                    w[i] = make_uint4(0u, 0u, 0u, 0u);
            }
            uint4* dst = (uint4*)&Bs[n][kc];
#pragma unroll
            for (int i = 0; i < 4; i++) dst[i] = w[i];
        }
        __syncthreads();
#pragma unroll
        for (int ks = 0; ks < 2; ks++) {
            int ko = ks * 32 + (lane >> 4) * 8;
            bf16x8 af[2], bfr[4];
#pragma unroll
            for (int f = 0; f < 2; f++)
                af[f] = *(const bf16x8*)&As[wm * 32 + f * 16 + (lane & 15)][ko];
#pragma unroll
            for (int g = 0; g < 4; g++)
                bfr[g] = *(const bf16x8*)&Bs[wn * 64 + g * 16 + (lane & 15)][ko];
#pragma unroll
            for (int f = 0; f < 2; f++)
#pragma unroll
                for (int g = 0; g < 4; g++)
                    acc[f][g] = __builtin_amdgcn_mfma_f32_16x16x32_bf16(
                        af[f], bfr[g], acc[f][g], 0, 0, 0);
        }
    }

#pragma unroll
    for (int g = 0; g < 4; g++) {
        int n = col0 + wn * 64 + g * 16 + (lane & 15);
        float bb = bias[n];
#pragma unroll
        for (int f = 0; f < 2; f++) {
#pragma unroll
            for (int r = 0; r < 4; r++) {
                int m = row0 + wm * 32 + f * 16 + (lane >> 4) * 4 + r;
                if (m < M) {
                    float v = acc[f][g][r] + bb;
                    if (RELU) v = fmaxf(v, 0.f);
                    if (OUTBF)
                        ((unsigned short*)Cv)[(size_t)m * 256 + n] = f2bf(v);
                    else
                        ((float*)Cv)[(size_t)m * 256 + n] = v;
                }
            }
        }
    }
}

// ---------------- pooling (two-stage, f32 input) ----------------
#define POOL_ROWS 64
__global__ __launch_bounds__(256) void k_pool_partial(const float* __restrict__ h,
                                                      const int* __restrict__ batch,
                                                      float* __restrict__ psum, int n) {
    int r0 = blockIdx.x * POOL_ROWS;
    int r1 = r0 + POOL_ROWS;
    if (r1 > n) r1 = n;
    if (r0 >= r1) return;
    int c = threadIdx.x;
    float acc = 0.f;
    int g = batch[r0];
    for (int r = r0; r < r1; r++) {
        int gr = batch[r];
        if (gr != g) {
            atomicAdd(&psum[g * 256 + c], acc);
            acc = 0.f;
            g = gr;
        }
        acc += h[(size_t)r * 256 + c];
    }
    atomicAdd(&psum[g * 256 + c], acc);
}

__device__ __forceinline__ int lower_bound_i(const int* __restrict__ a, int n, int v) {
    int lo = 0, hi = n;
    while (lo < hi) {
        int mid = (lo + hi) >> 1;
        if (a[mid] < v) lo = mid + 1; else hi = mid;
    }
    return lo;
}

__global__ __launch_bounds__(128) void k_head(const float* __restrict__ psum,
                                              const int* __restrict__ batch,
                                              const float* __restrict__ Wl,
                                              const float* __restrict__ bl,
                                              float* __restrict__ out, int n) {
    int tid = threadIdx.x;
    int g = tid >> 1, o = tid & 1;
    int s = lower_bound_i(batch, n, g);
    int e = lower_bound_i(batch, n, g + 1);
    float inv = 1.0f / (float)((e - s) > 1 ? (e - s) : 1);
    float sum = bl[o];
    for (int k = 0; k < 256; k++)
        sum = fmaf(psum[g * 256 + k] * inv, Wl[k * 2 + o], sum);
    out[g * 2 + o] = sum;
}

// ---------------- launch ----------------
extern "C" void kernel_launch(void* const* d_in, const int* in_sizes, int n_in,
                              void* d_out, int out_size, void* d_ws, size_t ws_size,
                              hipStream_t stream) {
    const float* x = (const float*)d_in[0];
    const int* ei = (const int*)d_in[1];
    const int* batch = (const int*)d_in[2];
    const float* W1 = (const float*)d_in[3];
    const float* b1 = (const float*)d_in[4];
    const float* W2 = (const float*)d_in[5];
    const float* b2 = (const float*)d_in[6];
    const float* V1 = (const float*)d_in[7];
    const float* c1 = (const float*)d_in[8];
    const float* V2 = (const float*)d_in[9];
    const float* c2 = (const float*)d_in[10];
    const float* Wl = (const float*)d_in[11];
    const float* bl = (const float*)d_in[12];
    float* out = (float*)d_out;

    const int* srcp = ei;
    const int* dstp = ei + N_EDGES;

    char* ws = (char*)d_ws;
    size_t off = 0;
    auto alloc = [&](size_t bytes) {
        size_t o = off;
        off = (off + bytes + 255) & ~(size_t)255;
        return o;
    };
    size_t o_deg = alloc(sizeof(int) * (N_NODES + 1));
    size_t o_rp = alloc(sizeof(int) * (N_NODES + 1));
    size_t o_wp = alloc(sizeof(int) * (N_NODES + 1));
    size_t o_bsum = alloc(sizeof(int) * SCAN_NB);
    size_t o_csr = alloc(sizeof(int) * N_EDGES);
    size_t o_B1 = alloc(sizeof(unsigned short) * (size_t)N_NODES * D_HID);
    size_t o_B2 = alloc(sizeof(unsigned short) * (size_t)N_NODES * D_HID);
    size_t o_h2 = alloc(sizeof(float) * (size_t)N_NODES * D_HID);
    size_t o_pool = alloc(sizeof(float) * N_GRAPHS * D_HID);
    size_t o_wt1 = alloc(sizeof(unsigned short) * D_IN * D_HID);
    size_t o_wt2 = alloc(sizeof(unsigned short) * D_HID * D_HID);
    size_t o_wv1 = alloc(sizeof(unsigned short) * D_HID * D_HID);
    size_t o_wv2 = alloc(sizeof(unsigned short) * D_HID * D_HID);
    (void)ws_size;

    int* deg = (int*)(ws + o_deg);
    int* rp = (int*)(ws + o_rp);
    int* wp = (int*)(ws + o_wp);
    int* bsum = (int*)(ws + o_bsum);
    int* csr = (int*)(ws + o_csr);
    unsigned short* B1 = (unsigned short*)(ws + o_B1);
    unsigned short* B2 = (unsigned short*)(ws + o_B2);
    float* h2 = (float*)(ws + o_h2);
    float* psum = (float*)(ws + o_pool);
    unsigned short* wt1 = (unsigned short*)(ws + o_wt1);
    unsigned short* wt2 = (unsigned short*)(ws + o_wt2);
    unsigned short* wv1 = (unsigned short*)(ws + o_wv1);
    unsigned short* wv2 = (unsigned short*)(ws + o_wv2);

    hipMemsetAsync(deg, 0, sizeof(int) * (N_NODES + 1), stream);
    hipMemsetAsync(psum, 0, sizeof(float) * N_GRAPHS * D_HID, stream);

    k_wt<<<D_IN, 256, 0, stream>>>(W1, wt1, D_IN);
    k_wt<<<D_HID, 256, 0, stream>>>(W2, wt2, D_HID);
    k_wt<<<D_HID, 256, 0, stream>>>(V1, wv1, D_HID);
    k_wt<<<D_HID, 256, 0, stream>>>(V2, wv2, D_HID);

    k_count<<<(N_EDGES + 255) / 256, 256, 0, stream>>>(dstp, deg, N_EDGES);
    k_scan1<<<SCAN_NB, 256, 0, stream>>>(deg, bsum, N_NODES);
    k_scan2<<<1, 256, 0, stream>>>(bsum, SCAN_NB);
    k_scan3<<<SCAN_NB, 256, 0, stream>>>(deg, bsum, rp, wp, N_NODES);
    k_scatter<<<(N_EDGES + 255) / 256, 256, 0, stream>>>(srcp, dstp, wp, csr, N_EDGES);

    // x -> bf16 (into B1)
    k_x2bf<<<(N_NODES * D_IN / 4 + 255) / 256, 256, 0, stream>>>(x, B1, N_NODES * D_IN / 4);

    dim3 ggrid((N_NODES + 63) / 64, 2);

    // layer 1: h0 = xb + agg(xb) -> B2; t1 = relu(h0@W1+b1) -> B1; h1 = relu(t1@W2+b2) -> B2
    k_agg96b<<<(N_NODES + 3) / 4, 256, 0, stream>>>(B1, rp, csr, B2, N_NODES);
    gemm_mfma<96, true, true><<<ggrid, 256, 0, stream>>>(B2, wt1, b1, B1, N_NODES);
    gemm_mfma<256, true, true><<<ggrid, 256, 0, stream>>>(B1, wt2, b2, B2, N_NODES);

    // layer 2: g2 = h1 + agg(h1) -> B1; t2 = relu(g2@V1+c1) -> B2; h2 = t2@V2+c2 -> h2(f32)
    k_agg256b<<<(N_NODES + 3) / 4, 256, 0, stream>>>(B2, rp, csr, B1, N_NODES);
    gemm_mfma<256, true, true><<<ggrid, 256, 0, stream>>>(B1, wv1, c1, B2, N_NODES);
    gemm_mfma<256, false, false><<<ggrid, 256, 0, stream>>>(B2, wv2, c2, h2, N_NODES);

    // pool + head
    k_pool_partial<<<(N_NODES + POOL_ROWS - 1) / POOL_ROWS, 256, 0, stream>>>(
        h2, batch, psum, N_NODES);
    k_head<<<1, 128, 0, stream>>>(psum, batch, Wl, bl, out, N_NODES);
}

// Round 12
// 338.632 us; speedup vs baseline: 2.9755x; 1.0356x over previous
//
// v12 — (a) 2x-unrolled agg kernels (2 independent gathers in flight per half-wave;
// v11 showed agg is still issue-limited at 42% BW), (b) final GEMM writes bf16 and
// pool reads bf16 (saves ~50MB h2 f32 round-trip). Everything else identical to v11.
#include <hip/hip_runtime.h>

#define N_NODES 50000
#define N_EDGES 800000
#define D_IN 96
#define D_HID 256
#define N_GRAPHS 64

#define SCAN_NB ((N_NODES + 255) / 256)

typedef __attribute__((ext_vector_type(8))) short bf16x8;
typedef __attribute__((ext_vector_type(4))) float f32x4;

__device__ __forceinline__ unsigned short f2bf(float f) {
    union { float f; unsigned int u; } v; v.f = f;
    unsigned int r = (v.u + 0x7FFFu + ((v.u >> 16) & 1u)) >> 16;  // RNE
    return (unsigned short)r;
}
__device__ __forceinline__ float bfLo(unsigned int u) {
    union { unsigned int u; float f; } v; v.u = u << 16; return v.f;
}
__device__ __forceinline__ float bfHi(unsigned int u) {
    union { unsigned int u; float f; } v; v.u = u & 0xFFFF0000u; return v.f;
}
__device__ __forceinline__ unsigned int packbf(float a, float b) {
    return (unsigned int)f2bf(a) | ((unsigned int)f2bf(b) << 16);
}

// ---------------- CSR build ----------------
__global__ void k_count(const int* __restrict__ dst, int* __restrict__ deg, int E) {
    int e = blockIdx.x * blockDim.x + threadIdx.x;
    if (e < E) atomicAdd(&deg[dst[e]], 1);
}

__global__ __launch_bounds__(256) void k_scan1(const int* __restrict__ deg,
                                               int* __restrict__ bsum, int n) {
    __shared__ int red[256];
    int tid = threadIdx.x;
    int i = blockIdx.x * 256 + tid;
    red[tid] = (i < n) ? deg[i] : 0;
    __syncthreads();
    for (int off = 128; off > 0; off >>= 1) {
        if (tid < off) red[tid] += red[tid + off];
        __syncthreads();
    }
    if (tid == 0) bsum[blockIdx.x] = red[0];
}

__global__ __launch_bounds__(256) void k_scan2(int* __restrict__ bsum, int nb) {
    __shared__ int s[256];
    int tid = threadIdx.x;
    int v = (tid < nb) ? bsum[tid] : 0;
    s[tid] = v;
    __syncthreads();
    for (int off = 1; off < 256; off <<= 1) {
        int t = (tid >= off) ? s[tid - off] : 0;
        __syncthreads();
        s[tid] += t;
        __syncthreads();
    }
    if (tid < nb) bsum[tid] = s[tid] - v;
}

__global__ __launch_bounds__(256) void k_scan3(const int* __restrict__ deg,
                                               const int* __restrict__ bsum,
                                               int* __restrict__ rp,
                                               int* __restrict__ wp, int n) {
    __shared__ int s[256];
    int tid = threadIdx.x;
    int i = blockIdx.x * 256 + tid;
    int v = (i < n) ? deg[i] : 0;
    s[tid] = v;
    __syncthreads();
    for (int off = 1; off < 256; off <<= 1) {
        int t = (tid >= off) ? s[tid - off] : 0;
        __syncthreads();
        s[tid] += t;
        __syncthreads();
    }
    if (i < n) {
        int excl = s[tid] - v + bsum[blockIdx.x];
        rp[i] = excl;
        wp[i] = excl;
    }
    if (blockIdx.x == 0 && tid == 0) rp[n] = N_EDGES;
}

__global__ void k_scatter(const int* __restrict__ src, const int* __restrict__ dst,
                          int* __restrict__ wp, int* __restrict__ csr, int E) {
    int e = blockIdx.x * blockDim.x + threadIdx.x;
    if (e < E) {
        int p = atomicAdd(&wp[dst[e]], 1);
        csr[p] = src[e];
    }
}

// ---------------- x f32 -> bf16 ----------------
__global__ __launch_bounds__(256) void k_x2bf(const float* __restrict__ x,
                                              unsigned short* __restrict__ xb, int n4) {
    int i = blockIdx.x * 256 + threadIdx.x;
    if (i >= n4) return;
    float4 v = ((const float4*)x)[i];
    ((uint2*)xb)[i] = make_uint2(packbf(v.x, v.y), packbf(v.z, v.w));
}

#define ACCUM(acc, v)                                    \
    do {                                                 \
        acc[0] += bfLo((v).x); acc[1] += bfHi((v).x);    \
        acc[2] += bfLo((v).y); acc[3] += bfHi((v).y);    \
        acc[4] += bfLo((v).z); acc[5] += bfHi((v).z);    \
        acc[6] += bfLo((v).w); acc[7] += bfHi((v).w);    \
    } while (0)

// ---------------- aggregation ----------------
// D=96 bf16: row = 192B = 12 uint4. 4 groups x 12 lanes; 2x unroll -> 8 edges/iter/wave.
__global__ __launch_bounds__(256) void k_agg96b(const unsigned short* __restrict__ xb,
                                                const int* __restrict__ rp,
                                                const int* __restrict__ csr,
                                                unsigned short* __restrict__ h0, int n) {
    int wid = blockIdx.x * 4 + (threadIdx.x >> 6);
    if (wid >= n) return;
    int lane = threadIdx.x & 63;
    int grp = lane / 12;       // 0..3 active, 4..5 idle
    int sub = lane % 12;
    int s = rp[wid], e = rp[wid + 1];
    const uint4* xp = (const uint4*)xb;  // row stride = 12 uint4
    float a[8] = {0.f, 0.f, 0.f, 0.f, 0.f, 0.f, 0.f, 0.f};
    float b[8] = {0.f, 0.f, 0.f, 0.f, 0.f, 0.f, 0.f, 0.f};
    if (lane < 48) {
        int j = s + grp;
        for (; j + 4 < e; j += 8) {
            int sc0 = csr[j];
            int sc1 = csr[j + 4];
            uint4 v0 = xp[(size_t)sc0 * 12 + sub];
            uint4 v1 = xp[(size_t)sc1 * 12 + sub];
            ACCUM(a, v0);
            ACCUM(b, v1);
        }
        if (j < e) {
            int sc0 = csr[j];
            uint4 v0 = xp[(size_t)sc0 * 12 + sub];
            ACCUM(a, v0);
        }
    }
#pragma unroll
    for (int i = 0; i < 8; i++) a[i] += b[i];
    // group-tree reduce: (g0+=g2, g1+=g3), then g0+=g1. Lanes >=48 hold zeros.
#pragma unroll
    for (int i = 0; i < 8; i++) a[i] += __shfl(a[i], lane + 24, 64);
#pragma unroll
    for (int i = 0; i < 8; i++) a[i] += __shfl(a[i], lane + 12, 64);
    if (lane < 12) {
        uint4 v = xp[(size_t)wid * 12 + sub];  // self row
        ACCUM(a, v);
        uint4 o;
        o.x = packbf(a[0], a[1]); o.y = packbf(a[2], a[3]);
        o.z = packbf(a[4], a[5]); o.w = packbf(a[6], a[7]);
        ((uint4*)h0)[(size_t)wid * 12 + sub] = o;
    }
}

// D=256 bf16: row = 512B = 32 uint4. 2 half-waves; 2x unroll -> 4 edges/iter/wave.
__global__ __launch_bounds__(256) void k_agg256b(const unsigned short* __restrict__ h,
                                                 const int* __restrict__ rp,
                                                 const int* __restrict__ csr,
                                                 unsigned short* __restrict__ outb, int n) {
    int wid = blockIdx.x * 4 + (threadIdx.x >> 6);
    if (wid >= n) return;
    int lane = threadIdx.x & 63;
    int half = lane >> 5;
    int sub = lane & 31;
    int s = rp[wid], e = rp[wid + 1];
    const uint4* hp = (const uint4*)h;  // row stride = 32 uint4
    float a[8] = {0.f, 0.f, 0.f, 0.f, 0.f, 0.f, 0.f, 0.f};
    float b[8] = {0.f, 0.f, 0.f, 0.f, 0.f, 0.f, 0.f, 0.f};
    int j = s + half;
    for (; j + 2 < e; j += 4) {
        int sc0 = csr[j];
        int sc1 = csr[j + 2];
        uint4 v0 = hp[(size_t)sc0 * 32 + sub];
        uint4 v1 = hp[(size_t)sc1 * 32 + sub];
        ACCUM(a, v0);
        ACCUM(b, v1);
    }
    if (j < e) {
        int sc0 = csr[j];
        uint4 v0 = hp[(size_t)sc0 * 32 + sub];
        ACCUM(a, v0);
    }
#pragma unroll
    for (int i = 0; i < 8; i++) a[i] += b[i];
    // cross-half reduce: half0 lane gets half1 partial
#pragma unroll
    for (int i = 0; i < 8; i++) a[i] += __shfl(a[i], sub + 32, 64);
    if (half == 0) {
        uint4 v = hp[(size_t)wid * 32 + sub];  // self row
        ACCUM(a, v);
        uint4 o;
        o.x = packbf(a[0], a[1]); o.y = packbf(a[2], a[3]);
        o.z = packbf(a[4], a[5]); o.w = packbf(a[6], a[7]);
        ((uint4*)outb)[(size_t)wid * 32 + sub] = o;
    }
}

// ---------------- weight transpose + bf16: W[K][256] -> Wt[256][K] ----------------
__global__ __launch_bounds__(256) void k_wt(const float* __restrict__ W,
                                            unsigned short* __restrict__ Wt, int K) {
    int idx = blockIdx.x * 256 + threadIdx.x;
    if (idx >= K * 256) return;
    int k = idx >> 8;
    int n = idx & 255;
    Wt[(size_t)n * K + k] = f2bf(W[idx]);
}

// ---------------- MFMA bf16 GEMM (unchanged from v9) ----------------
template <int K, bool RELU, bool OUTBF>
__global__ __launch_bounds__(256) void gemm_mfma(const unsigned short* __restrict__ A,
                                                 const unsigned short* __restrict__ Wt,
                                                 const float* __restrict__ bias,
                                                 void* __restrict__ Cv, int M) {
    constexpr int BM = 64, BN = 128, BK = 64;
    __shared__ unsigned short As[BM][BK + 8];
    __shared__ unsigned short Bs[BN][BK + 8];
    const int tid = threadIdx.x;
    const int lane = tid & 63;
    const int wid = tid >> 6;
    const int wm = wid >> 1;
    const int wn = wid & 1;
    const int row0 = blockIdx.x * BM;
    const int col0 = blockIdx.y * BN;

    f32x4 acc[2][4];
#pragma unroll
    for (int f = 0; f < 2; f++)
#pragma unroll
        for (int g = 0; g < 4; g++) acc[f][g] = (f32x4){0.f, 0.f, 0.f, 0.f};

    for (int kt = 0; kt < K; kt += BK) {
        __syncthreads();
        {
            int m = tid >> 2;
            int kc = (tid & 3) * 16;
            int gr = row0 + m;
            uint4 w0 = make_uint4(0u, 0u, 0u, 0u), w1 = w0;
            int k = kt + kc;
            if (gr < M && k < K) {
                w0 = *(const uint4*)&A[(size_t)gr * K + k];
                if (k + 8 < K) w1 = *(const uint4*)&A[(size_t)gr * K + k + 8];
            }
            uint4* dst = (uint4*)&As[m][kc];
            dst[0] = w0; dst[1] = w1;
        }
        {
            int n = tid >> 1;
            int kc = (tid & 1) * 32;
            uint4 w[4];
#pragma unroll
            for (int i = 0; i < 4; i++) {
                int k = kt + kc + i * 8;
                if (k < K)
                    w[i] = *(const uint4*)&Wt[(size_t)(col0 + n) * K + k];
                else
                    w[i] = make_uint4(0u, 0u, 0u, 0u);
            }
            uint4* dst = (uint4*)&Bs[n][kc];
#pragma unroll
            for (int i = 0; i < 4; i++) dst[i] = w[i];
        }
        __syncthreads();
#pragma unroll
        for (int ks = 0; ks < 2; ks++) {
            int ko = ks * 32 + (lane >> 4) * 8;
            bf16x8 af[2], bfr[4];
#pragma unroll
            for (int f = 0; f < 2; f++)
                af[f] = *(const bf16x8*)&As[wm * 32 + f * 16 + (lane & 15)][ko];
#pragma unroll
            for (int g = 0; g < 4; g++)
                bfr[g] = *(const bf16x8*)&Bs[wn * 64 + g * 16 + (lane & 15)][ko];
#pragma unroll
            for (int f = 0; f < 2; f++)
#pragma unroll
                for (int g = 0; g < 4; g++)
                    acc[f][g] = __builtin_amdgcn_mfma_f32_16x16x32_bf16(
                        af[f], bfr[g], acc[f][g], 0, 0, 0);
        }
    }

#pragma unroll
    for (int g = 0; g < 4; g++) {
        int n = col0 + wn * 64 + g * 16 + (lane & 15);
        float bb = bias[n];
#pragma unroll
        for (int f = 0; f < 2; f++) {
#pragma unroll
            for (int r = 0; r < 4; r++) {
                int m = row0 + wm * 32 + f * 16 + (lane >> 4) * 4 + r;
                if (m < M) {
                    float v = acc[f][g][r] + bb;
                    if (RELU) v = fmaxf(v, 0.f);
                    if (OUTBF)
                        ((unsigned short*)Cv)[(size_t)m * 256 + n] = f2bf(v);
                    else
                        ((float*)Cv)[(size_t)m * 256 + n] = v;
                }
            }
        }
    }
}

// ---------------- pooling (two-stage, bf16 input) ----------------
#define POOL_ROWS 64
__global__ __launch_bounds__(256) void k_pool_partial(const unsigned short* __restrict__ h,
                                                      const int* __restrict__ batch,
                                                      float* __restrict__ psum, int n) {
    int r0 = blockIdx.x * POOL_ROWS;
    int r1 = r0 + POOL_ROWS;
    if (r1 > n) r1 = n;
    if (r0 >= r1) return;
    int c = threadIdx.x;
    float acc = 0.f;
    int g = batch[r0];
    for (int r = r0; r < r1; r++) {
        int gr = batch[r];
        if (gr != g) {
            atomicAdd(&psum[g * 256 + c], acc);
            acc = 0.f;
            g = gr;
        }
        acc += bfLo((unsigned int)h[(size_t)r * 256 + c]);
    }
    atomicAdd(&psum[g * 256 + c], acc);
}

__device__ __forceinline__ int lower_bound_i(const int* __restrict__ a, int n, int v) {
    int lo = 0, hi = n;
    while (lo < hi) {
        int mid = (lo + hi) >> 1;
        if (a[mid] < v) lo = mid + 1; else hi = mid;
    }
    return lo;
}

__global__ __launch_bounds__(128) void k_head(const float* __restrict__ psum,
                                              const int* __restrict__ batch,
                                              const float* __restrict__ Wl,
                                              const float* __restrict__ bl,
                                              float* __restrict__ out, int n) {
    int tid = threadIdx.x;
    int g = tid >> 1, o = tid & 1;
    int s = lower_bound_i(batch, n, g);
    int e = lower_bound_i(batch, n, g + 1);
    float inv = 1.0f / (float)((e - s) > 1 ? (e - s) : 1);
    float sum = bl[o];
    for (int k = 0; k < 256; k++)
        sum = fmaf(psum[g * 256 + k] * inv, Wl[k * 2 + o], sum);
    out[g * 2 + o] = sum;
}

// ---------------- launch ----------------
extern "C" void kernel_launch(void* const* d_in, const int* in_sizes, int n_in,
                              void* d_out, int out_size, void* d_ws, size_t ws_size,
                              hipStream_t stream) {
    const float* x = (const float*)d_in[0];
    const int* ei = (const int*)d_in[1];
    const int* batch = (const int*)d_in[2];
    const float* W1 = (const float*)d_in[3];
    const float* b1 = (const float*)d_in[4];
    const float* W2 = (const float*)d_in[5];
    const float* b2 = (const float*)d_in[6];
    const float* V1 = (const float*)d_in[7];
    const float* c1 = (const float*)d_in[8];
    const float* V2 = (const float*)d_in[9];
    const float* c2 = (const float*)d_in[10];
    const float* Wl = (const float*)d_in[11];
    const float* bl = (const float*)d_in[12];
    float* out = (float*)d_out;

    const int* srcp = ei;
    const int* dstp = ei + N_EDGES;

    char* ws = (char*)d_ws;
    size_t off = 0;
    auto alloc = [&](size_t bytes) {
        size_t o = off;
        off = (off + bytes + 255) & ~(size_t)255;
        return o;
    };
    size_t o_deg = alloc(sizeof(int) * (N_NODES + 1));
    size_t o_rp = alloc(sizeof(int) * (N_NODES + 1));
    size_t o_wp = alloc(sizeof(int) * (N_NODES + 1));
    size_t o_bsum = alloc(sizeof(int) * SCAN_NB);
    size_t o_csr = alloc(sizeof(int) * N_EDGES);
    size_t o_B1 = alloc(sizeof(unsigned short) * (size_t)N_NODES * D_HID);
    size_t o_B2 = alloc(sizeof(unsigned short) * (size_t)N_NODES * D_HID);
    size_t o_pool = alloc(sizeof(float) * N_GRAPHS * D_HID);
    size_t o_wt1 = alloc(sizeof(unsigned short) * D_IN * D_HID);
    size_t o_wt2 = alloc(sizeof(unsigned short) * D_HID * D_HID);
    size_t o_wv1 = alloc(sizeof(unsigned short) * D_HID * D_HID);
    size_t o_wv2 = alloc(sizeof(unsigned short) * D_HID * D_HID);
    (void)ws_size;

    int* deg = (int*)(ws + o_deg);
    int* rp = (int*)(ws + o_rp);
    int* wp = (int*)(ws + o_wp);
    int* bsum = (int*)(ws + o_bsum);
    int* csr = (int*)(ws + o_csr);
    unsigned short* B1 = (unsigned short*)(ws + o_B1);
    unsigned short* B2 = (unsigned short*)(ws + o_B2);
    float* psum = (float*)(ws + o_pool);
    unsigned short* wt1 = (unsigned short*)(ws + o_wt1);
    unsigned short* wt2 = (unsigned short*)(ws + o_wt2);
    unsigned short* wv1 = (unsigned short*)(ws + o_wv1);
    unsigned short* wv2 = (unsigned short*)(ws + o_wv2);

    hipMemsetAsync(deg, 0, sizeof(int) * (N_NODES + 1), stream);
    hipMemsetAsync(psum, 0, sizeof(float) * N_GRAPHS * D_HID, stream);

    k_wt<<<D_IN, 256, 0, stream>>>(W1, wt1, D_IN);
    k_wt<<<D_HID, 256, 0, stream>>>(W2, wt2, D_HID);
    k_wt<<<D_HID, 256, 0, stream>>>(V1, wv1, D_HID);
    k_wt<<<D_HID, 256, 0, stream>>>(V2, wv2, D_HID);

    k_count<<<(N_EDGES + 255) / 256, 256, 0, stream>>>(dstp, deg, N_EDGES);
    k_scan1<<<SCAN_NB, 256, 0, stream>>>(deg, bsum, N_NODES);
    k_scan2<<<1, 256, 0, stream>>>(bsum, SCAN_NB);
    k_scan3<<<SCAN_NB, 256, 0, stream>>>(deg, bsum, rp, wp, N_NODES);
    k_scatter<<<(N_EDGES + 255) / 256, 256, 0, stream>>>(srcp, dstp, wp, csr, N_EDGES);

    // x -> bf16 (into B1)
    k_x2bf<<<(N_NODES * D_IN / 4 + 255) / 256, 256, 0, stream>>>(x, B1, N_NODES * D_IN / 4);

    dim3 ggrid((N_NODES + 63) / 64, 2);

    // layer 1: h0 = xb + agg(xb) -> B2; t1 = relu(h0@W1+b1) -> B1; h1 = relu(t1@W2+b2) -> B2
    k_agg96b<<<(N_NODES + 3) / 4, 256, 0, stream>>>(B1, rp, csr, B2, N_NODES);
    gemm_mfma<96, true, true><<<ggrid, 256, 0, stream>>>(B2, wt1, b1, B1, N_NODES);
    gemm_mfma<256, true, true><<<ggrid, 256, 0, stream>>>(B1, wt2, b2, B2, N_NODES);

    // layer 2: g2 = h1 + agg(h1) -> B1; t2 = relu(g2@V1+c1) -> B2; h2(bf16) = t2@V2+c2 -> B1
    k_agg256b<<<(N_NODES + 3) / 4, 256, 0, stream>>>(B2, rp, csr, B1, N_NODES);
    gemm_mfma<256, true, true><<<ggrid, 256, 0, stream>>>(B1, wv1, c1, B2, N_NODES);
    gemm_mfma<256, false, true><<<ggrid, 256, 0, stream>>>(B2, wv2, c2, B1, N_NODES);

    // pool + head
    k_pool_partial<<<(N_NODES + POOL_ROWS - 1) / POOL_ROWS, 256, 0, stream>>>(
        B1, batch, psum, N_NODES);
    k_head<<<1, 128, 0, stream>>>(psum, batch, Wl, bl, out, N_NODES);
}

// Round 13
// 333.095 us; speedup vs baseline: 3.0249x; 1.0166x over previous
//
// v13 — fuse each GIN-layer MLP (two GEMMs) into one kernel: GEMM1 -> relu/bf16 ->
// LDS tile -> GEMM2, eliminating the 25.6MB t1/t2 global round-trips and 2 dispatches.
// agg kernels, CSR build, pooling unchanged from v12 (agg256b is at its compulsory
// per-XCD traffic floor: FETCH 185MB = 8 XCDs x 25.6MB buffer).
#include <hip/hip_runtime.h>

#define N_NODES 50000
#define N_EDGES 800000
#define D_IN 96
#define D_HID 256
#define N_GRAPHS 64

#define SCAN_NB ((N_NODES + 255) / 256)

typedef __attribute__((ext_vector_type(8))) short bf16x8;
typedef __attribute__((ext_vector_type(4))) float f32x4;

__device__ __forceinline__ unsigned short f2bf(float f) {
    union { float f; unsigned int u; } v; v.f = f;
    unsigned int r = (v.u + 0x7FFFu + ((v.u >> 16) & 1u)) >> 16;  // RNE
    return (unsigned short)r;
}
__device__ __forceinline__ float bfLo(unsigned int u) {
    union { unsigned int u; float f; } v; v.u = u << 16; return v.f;
}
__device__ __forceinline__ float bfHi(unsigned int u) {
    union { unsigned int u; float f; } v; v.u = u & 0xFFFF0000u; return v.f;
}
__device__ __forceinline__ unsigned int packbf(float a, float b) {
    return (unsigned int)f2bf(a) | ((unsigned int)f2bf(b) << 16);
}

// ---------------- CSR build ----------------
__global__ void k_count(const int* __restrict__ dst, int* __restrict__ deg, int E) {
    int e = blockIdx.x * blockDim.x + threadIdx.x;
    if (e < E) atomicAdd(&deg[dst[e]], 1);
}

__global__ __launch_bounds__(256) void k_scan1(const int* __restrict__ deg,
                                               int* __restrict__ bsum, int n) {
    __shared__ int red[256];
    int tid = threadIdx.x;
    int i = blockIdx.x * 256 + tid;
    red[tid] = (i < n) ? deg[i] : 0;
    __syncthreads();
    for (int off = 128; off > 0; off >>= 1) {
        if (tid < off) red[tid] += red[tid + off];
        __syncthreads();
    }
    if (tid == 0) bsum[blockIdx.x] = red[0];
}

__global__ __launch_bounds__(256) void k_scan2(int* __restrict__ bsum, int nb) {
    __shared__ int s[256];
    int tid = threadIdx.x;
    int v = (tid < nb) ? bsum[tid] : 0;
    s[tid] = v;
    __syncthreads();
    for (int off = 1; off < 256; off <<= 1) {
        int t = (tid >= off) ? s[tid - off] : 0;
        __syncthreads();
        s[tid] += t;
        __syncthreads();
    }
    if (tid < nb) bsum[tid] = s[tid] - v;
}

__global__ __launch_bounds__(256) void k_scan3(const int* __restrict__ deg,
                                               const int* __restrict__ bsum,
                                               int* __restrict__ rp,
                                               int* __restrict__ wp, int n) {
    __shared__ int s[256];
    int tid = threadIdx.x;
    int i = blockIdx.x * 256 + tid;
    int v = (i < n) ? deg[i] : 0;
    s[tid] = v;
    __syncthreads();
    for (int off = 1; off < 256; off <<= 1) {
        int t = (tid >= off) ? s[tid - off] : 0;
        __syncthreads();
        s[tid] += t;
        __syncthreads();
    }
    if (i < n) {
        int excl = s[tid] - v + bsum[blockIdx.x];
        rp[i] = excl;
        wp[i] = excl;
    }
    if (blockIdx.x == 0 && tid == 0) rp[n] = N_EDGES;
}

__global__ void k_scatter(const int* __restrict__ src, const int* __restrict__ dst,
                          int* __restrict__ wp, int* __restrict__ csr, int E) {
    int e = blockIdx.x * blockDim.x + threadIdx.x;
    if (e < E) {
        int p = atomicAdd(&wp[dst[e]], 1);
        csr[p] = src[e];
    }
}

// ---------------- x f32 -> bf16 ----------------
__global__ __launch_bounds__(256) void k_x2bf(const float* __restrict__ x,
                                              unsigned short* __restrict__ xb, int n4) {
    int i = blockIdx.x * 256 + threadIdx.x;
    if (i >= n4) return;
    float4 v = ((const float4*)x)[i];
    ((uint2*)xb)[i] = make_uint2(packbf(v.x, v.y), packbf(v.z, v.w));
}

#define ACCUM(acc, v)                                    \
    do {                                                 \
        acc[0] += bfLo((v).x); acc[1] += bfHi((v).x);    \
        acc[2] += bfLo((v).y); acc[3] += bfHi((v).y);    \
        acc[4] += bfLo((v).z); acc[5] += bfHi((v).z);    \
        acc[6] += bfLo((v).w); acc[7] += bfHi((v).w);    \
    } while (0)

// ---------------- aggregation (unchanged from v12) ----------------
__global__ __launch_bounds__(256) void k_agg96b(const unsigned short* __restrict__ xb,
                                                const int* __restrict__ rp,
                                                const int* __restrict__ csr,
                                                unsigned short* __restrict__ h0, int n) {
    int wid = blockIdx.x * 4 + (threadIdx.x >> 6);
    if (wid >= n) return;
    int lane = threadIdx.x & 63;
    int grp = lane / 12;
    int sub = lane % 12;
    int s = rp[wid], e = rp[wid + 1];
    const uint4* xp = (const uint4*)xb;
    float a[8] = {0.f, 0.f, 0.f, 0.f, 0.f, 0.f, 0.f, 0.f};
    float b[8] = {0.f, 0.f, 0.f, 0.f, 0.f, 0.f, 0.f, 0.f};
    if (lane < 48) {
        int j = s + grp;
        for (; j + 4 < e; j += 8) {
            int sc0 = csr[j];
            int sc1 = csr[j + 4];
            uint4 v0 = xp[(size_t)sc0 * 12 + sub];
            uint4 v1 = xp[(size_t)sc1 * 12 + sub];
            ACCUM(a, v0);
            ACCUM(b, v1);
        }
        if (j < e) {
            int sc0 = csr[j];
            uint4 v0 = xp[(size_t)sc0 * 12 + sub];
            ACCUM(a, v0);
        }
    }
#pragma unroll
    for (int i = 0; i < 8; i++) a[i] += b[i];
#pragma unroll
    for (int i = 0; i < 8; i++) a[i] += __shfl(a[i], lane + 24, 64);
#pragma unroll
    for (int i = 0; i < 8; i++) a[i] += __shfl(a[i], lane + 12, 64);
    if (lane < 12) {
        uint4 v = xp[(size_t)wid * 12 + sub];
        ACCUM(a, v);
        uint4 o;
        o.x = packbf(a[0], a[1]); o.y = packbf(a[2], a[3]);
        o.z = packbf(a[4], a[5]); o.w = packbf(a[6], a[7]);
        ((uint4*)h0)[(size_t)wid * 12 + sub] = o;
    }
}

__global__ __launch_bounds__(256) void k_agg256b(const unsigned short* __restrict__ h,
                                                 const int* __restrict__ rp,
                                                 const int* __restrict__ csr,
                                                 unsigned short* __restrict__ outb, int n) {
    int wid = blockIdx.x * 4 + (threadIdx.x >> 6);
    if (wid >= n) return;
    int lane = threadIdx.x & 63;
    int half = lane >> 5;
    int sub = lane & 31;
    int s = rp[wid], e = rp[wid + 1];
    const uint4* hp = (const uint4*)h;
    float a[8] = {0.f, 0.f, 0.f, 0.f, 0.f, 0.f, 0.f, 0.f};
    float b[8] = {0.f, 0.f, 0.f, 0.f, 0.f, 0.f, 0.f, 0.f};
    int j = s + half;
    for (; j + 2 < e; j += 4) {
        int sc0 = csr[j];
        int sc1 = csr[j + 2];
        uint4 v0 = hp[(size_t)sc0 * 32 + sub];
        uint4 v1 = hp[(size_t)sc1 * 32 + sub];
        ACCUM(a, v0);
        ACCUM(b, v1);
    }
    if (j < e) {
        int sc0 = csr[j];
        uint4 v0 = hp[(size_t)sc0 * 32 + sub];
        ACCUM(a, v0);
    }
#pragma unroll
    for (int i = 0; i < 8; i++) a[i] += b[i];
#pragma unroll
    for (int i = 0; i < 8; i++) a[i] += __shfl(a[i], sub + 32, 64);
    if (half == 0) {
        uint4 v = hp[(size_t)wid * 32 + sub];
        ACCUM(a, v);
        uint4 o;
        o.x = packbf(a[0], a[1]); o.y = packbf(a[2], a[3]);
        o.z = packbf(a[4], a[5]); o.w = packbf(a[6], a[7]);
        ((uint4*)outb)[(size_t)wid * 32 + sub] = o;
    }
}

// ---------------- weight transpose + bf16: W[K][256] -> Wt[256][K] ----------------
__global__ __launch_bounds__(256) void k_wt(const float* __restrict__ W,
                                            unsigned short* __restrict__ Wt, int K) {
    int idx = blockIdx.x * 256 + threadIdx.x;
    if (idx >= K * 256) return;
    int k = idx >> 8;
    int n = idx & 255;
    Wt[(size_t)n * K + k] = f2bf(W[idx]);
}

// ---------------- fused MLP: C = act2(relu(A@W1+b1)@W2+b2), all bf16 io ----------------
// Block: 64 rows x 256 cols. 4 waves (2x2), wave tile 32x128 = acc[2][8] frags.
// GEMM1 accumulates -> relu+bf16 -> T1 in LDS -> GEMM2 reads A-frags from T1.
template <int K1, bool RELU2>
__global__ __launch_bounds__(256) void fused_mlp(const unsigned short* __restrict__ A,
                                                 const unsigned short* __restrict__ W1t,
                                                 const float* __restrict__ bias1,
                                                 const unsigned short* __restrict__ W2t,
                                                 const float* __restrict__ bias2,
                                                 unsigned short* __restrict__ C, int M) {
    __shared__ unsigned short As[64][72];
    __shared__ unsigned short Bs[256][72];
    __shared__ unsigned short T1[64][264];
    const int tid = threadIdx.x;
    const int lane = tid & 63;
    const int wid = tid >> 6;
    const int wm = wid >> 1;  // 0..1 (row half)
    const int wn = wid & 1;   // 0..1 (col half)
    const int row0 = blockIdx.x * 64;

    f32x4 acc[2][8];
#pragma unroll
    for (int f = 0; f < 2; f++)
#pragma unroll
        for (int g = 0; g < 8; g++) acc[f][g] = (f32x4){0.f, 0.f, 0.f, 0.f};

    // ---- GEMM1: acc = A[64 x K1] @ W1t^T ----
    for (int kt = 0; kt < K1; kt += 64) {
        __syncthreads();
        {   // stage A: thread t: m=t>>2, kc=(t&3)*16
            int m = tid >> 2;
            int kc = (tid & 3) * 16;
            int gr = row0 + m;
            uint4 w0 = make_uint4(0u, 0u, 0u, 0u), w1 = w0;
            int k = kt + kc;
            if (gr < M && k < K1) {
                w0 = *(const uint4*)&A[(size_t)gr * K1 + k];
                if (k + 8 < K1) w1 = *(const uint4*)&A[(size_t)gr * K1 + k + 8];
            }
            uint4* dst = (uint4*)&As[m][kc];
            dst[0] = w0; dst[1] = w1;
        }
#pragma unroll
        for (int p = 0; p < 2; p++) {  // stage B (W1t): 2x128 rows
            int n = (tid >> 1) + p * 128;
            int kc = (tid & 1) * 32;
            uint4 w[4];
#pragma unroll
            for (int i = 0; i < 4; i++) {
                int k = kt + kc + i * 8;
                w[i] = (k < K1) ? *(const uint4*)&W1t[(size_t)n * K1 + k]
                                : make_uint4(0u, 0u, 0u, 0u);
            }
            uint4* dst = (uint4*)&Bs[n][kc];
#pragma unroll
            for (int i = 0; i < 4; i++) dst[i] = w[i];
        }
        __syncthreads();
#pragma unroll
        for (int ks = 0; ks < 2; ks++) {
            int ko = ks * 32 + (lane >> 4) * 8;
            bf16x8 af[2], bfr[8];
#pragma unroll
            for (int f = 0; f < 2; f++)
                af[f] = *(const bf16x8*)&As[wm * 32 + f * 16 + (lane & 15)][ko];
#pragma unroll
            for (int g = 0; g < 8; g++)
                bfr[g] = *(const bf16x8*)&Bs[wn * 128 + g * 16 + (lane & 15)][ko];
#pragma unroll
            for (int f = 0; f < 2; f++)
#pragma unroll
                for (int g = 0; g < 8; g++)
                    acc[f][g] = __builtin_amdgcn_mfma_f32_16x16x32_bf16(
                        af[f], bfr[g], acc[f][g], 0, 0, 0);
        }
    }

    // ---- t1 = relu(acc + b1) -> T1 (bf16), then reset acc ----
#pragma unroll
    for (int g = 0; g < 8; g++) {
        int col = wn * 128 + g * 16 + (lane & 15);
        float bb = bias1[col];
#pragma unroll
        for (int f = 0; f < 2; f++) {
#pragma unroll
            for (int r = 0; r < 4; r++) {
                int row = wm * 32 + f * 16 + (lane >> 4) * 4 + r;
                float v = fmaxf(acc[f][g][r] + bb, 0.f);
                T1[row][col] = f2bf(v);
            }
        }
    }
#pragma unroll
    for (int f = 0; f < 2; f++)
#pragma unroll
        for (int g = 0; g < 8; g++) acc[f][g] = (f32x4){0.f, 0.f, 0.f, 0.f};

    // ---- GEMM2: acc = T1[64 x 256] @ W2t^T ----
    for (int kt = 0; kt < 256; kt += 64) {
        __syncthreads();  // first: T1 visible + GEMM1 Bs reads done; later: prev compute done
#pragma unroll
        for (int p = 0; p < 2; p++) {  // stage B (W2t)
            int n = (tid >> 1) + p * 128;
            int kc = (tid & 1) * 32;
            uint4 w[4];
#pragma unroll
            for (int i = 0; i < 4; i++) {
                int k = kt + kc + i * 8;
                w[i] = *(const uint4*)&W2t[(size_t)n * 256 + k];
            }
            uint4* dst = (uint4*)&Bs[n][kc];
#pragma unroll
            for (int i = 0; i < 4; i++) dst[i] = w[i];
        }
        __syncthreads();
#pragma unroll
        for (int ks = 0; ks < 2; ks++) {
            int ko = ks * 32 + (lane >> 4) * 8;
            bf16x8 af[2], bfr[8];
#pragma unroll
            for (int f = 0; f < 2; f++)
                af[f] = *(const bf16x8*)&T1[wm * 32 + f * 16 + (lane & 15)][kt + ko];
#pragma unroll
            for (int g = 0; g < 8; g++)
                bfr[g] = *(const bf16x8*)&Bs[wn * 128 + g * 16 + (lane & 15)][ko];
#pragma unroll
            for (int f = 0; f < 2; f++)
#pragma unroll
                for (int g = 0; g < 8; g++)
                    acc[f][g] = __builtin_amdgcn_mfma_f32_16x16x32_bf16(
                        af[f], bfr[g], acc[f][g], 0, 0, 0);
        }
    }

    // ---- epilogue: bias2 (+relu), bf16 store ----
#pragma unroll
    for (int g = 0; g < 8; g++) {
        int n = wn * 128 + g * 16 + (lane & 15);
        float bb = bias2[n];
#pragma unroll
        for (int f = 0; f < 2; f++) {
#pragma unroll
            for (int r = 0; r < 4; r++) {
                int m = row0 + wm * 32 + f * 16 + (lane >> 4) * 4 + r;
                if (m < M) {
                    float v = acc[f][g][r] + bb;
                    if (RELU2) v = fmaxf(v, 0.f);
                    C[(size_t)m * 256 + n] = f2bf(v);
                }
            }
        }
    }
}

// ---------------- pooling (two-stage, bf16 input) ----------------
#define POOL_ROWS 64
__global__ __launch_bounds__(256) void k_pool_partial(const unsigned short* __restrict__ h,
                                                      const int* __restrict__ batch,
                                                      float* __restrict__ psum, int n) {
    int r0 = blockIdx.x * POOL_ROWS;
    int r1 = r0 + POOL_ROWS;
    if (r1 > n) r1 = n;
    if (r0 >= r1) return;
    int c = threadIdx.x;
    float acc = 0.f;
    int g = batch[r0];
    for (int r = r0; r < r1; r++) {
        int gr = batch[r];
        if (gr != g) {
            atomicAdd(&psum[g * 256 + c], acc);
            acc = 0.f;
            g = gr;
        }
        acc += bfLo((unsigned int)h[(size_t)r * 256 + c]);
    }
    atomicAdd(&psum[g * 256 + c], acc);
}

__device__ __forceinline__ int lower_bound_i(const int* __restrict__ a, int n, int v) {
    int lo = 0, hi = n;
    while (lo < hi) {
        int mid = (lo + hi) >> 1;
        if (a[mid] < v) lo = mid + 1; else hi = mid;
    }
    return lo;
}

__global__ __launch_bounds__(128) void k_head(const float* __restrict__ psum,
                                              const int* __restrict__ batch,
                                              const float* __restrict__ Wl,
                                              const float* __restrict__ bl,
                                              float* __restrict__ out, int n) {
    int tid = threadIdx.x;
    int g = tid >> 1, o = tid & 1;
    int s = lower_bound_i(batch, n, g);
    int e = lower_bound_i(batch, n, g + 1);
    float inv = 1.0f / (float)((e - s) > 1 ? (e - s) : 1);
    float sum = bl[o];
    for (int k = 0; k < 256; k++)
        sum = fmaf(psum[g * 256 + k] * inv, Wl[k * 2 + o], sum);
    out[g * 2 + o] = sum;
}

// ---------------- launch ----------------
extern "C" void kernel_launch(void* const* d_in, const int* in_sizes, int n_in,
                              void* d_out, int out_size, void* d_ws, size_t ws_size,
                              hipStream_t stream) {
    const float* x = (const float*)d_in[0];
    const int* ei = (const int*)d_in[1];
    const int* batch = (const int*)d_in[2];
    const float* W1 = (const float*)d_in[3];
    const float* b1 = (const float*)d_in[4];
    const float* W2 = (const float*)d_in[5];
    const float* b2 = (const float*)d_in[6];
    const float* V1 = (const float*)d_in[7];
    const float* c1 = (const float*)d_in[8];
    const float* V2 = (const float*)d_in[9];
    const float* c2 = (const float*)d_in[10];
    const float* Wl = (const float*)d_in[11];
    const float* bl = (const float*)d_in[12];
    float* out = (float*)d_out;

    const int* srcp = ei;
    const int* dstp = ei + N_EDGES;

    char* ws = (char*)d_ws;
    size_t off = 0;
    auto alloc = [&](size_t bytes) {
        size_t o = off;
        off = (off + bytes + 255) & ~(size_t)255;
        return o;
    };
    size_t o_deg = alloc(sizeof(int) * (N_NODES + 1));
    size_t o_rp = alloc(sizeof(int) * (N_NODES + 1));
    size_t o_wp = alloc(sizeof(int) * (N_NODES + 1));
    size_t o_bsum = alloc(sizeof(int) * SCAN_NB);
    size_t o_csr = alloc(sizeof(int) * N_EDGES);
    size_t o_B1 = alloc(sizeof(unsigned short) * (size_t)N_NODES * D_HID);
    size_t o_B2 = alloc(sizeof(unsigned short) * (size_t)N_NODES * D_HID);
    size_t o_pool = alloc(sizeof(float) * N_GRAPHS * D_HID);
    size_t o_wt1 = alloc(sizeof(unsigned short) * D_IN * D_HID);
    size_t o_wt2 = alloc(sizeof(unsigned short) * D_HID * D_HID);
    size_t o_wv1 = alloc(sizeof(unsigned short) * D_HID * D_HID);
    size_t o_wv2 = alloc(sizeof(unsigned short) * D_HID * D_HID);
    (void)ws_size;

    int* deg = (int*)(ws + o_deg);
    int* rp = (int*)(ws + o_rp);
    int* wp = (int*)(ws + o_wp);
    int* bsum = (int*)(ws + o_bsum);
    int* csr = (int*)(ws + o_csr);
    unsigned short* B1 = (unsigned short*)(ws + o_B1);
    unsigned short* B2 = (unsigned short*)(ws + o_B2);
    float* psum = (float*)(ws + o_pool);
    unsigned short* wt1 = (unsigned short*)(ws + o_wt1);
    unsigned short* wt2 = (unsigned short*)(ws + o_wt2);
    unsigned short* wv1 = (unsigned short*)(ws + o_wv1);
    unsigned short* wv2 = (unsigned short*)(ws + o_wv2);

    hipMemsetAsync(deg, 0, sizeof(int) * (N_NODES + 1), stream);
    hipMemsetAsync(psum, 0, sizeof(float) * N_GRAPHS * D_HID, stream);

    k_wt<<<D_IN, 256, 0, stream>>>(W1, wt1, D_IN);
    k_wt<<<D_HID, 256, 0, stream>>>(W2, wt2, D_HID);
    k_wt<<<D_HID, 256, 0, stream>>>(V1, wv1, D_HID);
    k_wt<<<D_HID, 256, 0, stream>>>(V2, wv2, D_HID);

    k_count<<<(N_EDGES + 255) / 256, 256, 0, stream>>>(dstp, deg, N_EDGES);
    k_scan1<<<SCAN_NB, 256, 0, stream>>>(deg, bsum, N_NODES);
    k_scan2<<<1, 256, 0, stream>>>(bsum, SCAN_NB);
    k_scan3<<<SCAN_NB, 256, 0, stream>>>(deg, bsum, rp, wp, N_NODES);
    k_scatter<<<(N_EDGES + 255) / 256, 256, 0, stream>>>(srcp, dstp, wp, csr, N_EDGES);

    // x -> bf16 (into B1)
    k_x2bf<<<(N_NODES * D_IN / 4 + 255) / 256, 256, 0, stream>>>(x, B1, N_NODES * D_IN / 4);

    int mlpgrid = (N_NODES + 63) / 64;

    // layer 1: h0 = xb + agg(xb) -> B2; h1 = relu(relu(h0@W1+b1)@W2+b2) -> B1
    k_agg96b<<<(N_NODES + 3) / 4, 256, 0, stream>>>(B1, rp, csr, B2, N_NODES);
    fused_mlp<96, true><<<mlpgrid, 256, 0, stream>>>(B2, wt1, b1, wt2, b2, B1, N_NODES);

    // layer 2: g2 = h1 + agg(h1) -> B2; h2 = relu(g2@V1+c1)@V2+c2 -> B1 (bf16)
    k_agg256b<<<(N_NODES + 3) / 4, 256, 0, stream>>>(B1, rp, csr, B2, N_NODES);
    fused_mlp<256, false><<<mlpgrid, 256, 0, stream>>>(B2, wv1, c1, wv2, c2, B1, N_NODES);

    // pool + head
    k_pool_partial<<<(N_NODES + POOL_ROWS - 1) / POOL_ROWS, 256, 0, stream>>>(
        B1, batch, psum, N_NODES);
    k_head<<<1, 128, 0, stream>>>(psum, batch, Wl, bl, out, N_NODES);
}